// Round 4
// baseline (3202.669 us; speedup 1.0000x reference)
//
#include <hip/hip_runtime.h>
#include <math.h>

#define BATCH 128
#define DMODEL 512
#define NHEAD 8
#define NLAYER 6
#define SEQ 200
#define LATDIM 256
#define OUTDIM 6
#define DFF 2048
#define ROWS (BATCH * SEQ)   // 25600
#define QKVS 1536            // fused qkv row stride
#define VTS 264              // Vt row stride (u16): 528B, bank-rotating

typedef unsigned short u16;
typedef __attribute__((ext_vector_type(8))) short bfrag8;
typedef __attribute__((ext_vector_type(4))) float facc4;

// branch-free erf (Abramowitz-Stegun 7.1.26, |err| <= 1.5e-7) -> cheap exact-gelu
__device__ __forceinline__ float gelu_f(float v) {
    const float x = v * 0.70710678118654752f;
    const float ax = fabsf(x);
    const float t = __builtin_amdgcn_rcpf(fmaf(0.3275911f, ax, 1.0f));
    float p = fmaf(1.061405429f, t, -1.453152027f);
    p = fmaf(p, t, 1.421413741f);
    p = fmaf(p, t, -0.284496736f);
    p = fmaf(p, t, 0.254829592f);
    p = p * t;
    const float e = __expf(-ax * ax);
    float er = fmaf(-p, e, 1.0f);          // erf(|x|)
    er = copysignf(er, x);
    return 0.5f * v * (1.0f + er);
}
__device__ __forceinline__ u16 f2bf(float f) {
    unsigned u = __float_as_uint(f);
    u += 0x7fffu + ((u >> 16) & 1u);
    return (u16)(u >> 16);
}
// async global->LDS, 16B per lane; HW dest = wave-uniform base + lane*16
__device__ __forceinline__ void gl_lds16(const u16* g, u16* l) {
    __builtin_amdgcn_global_load_lds(
        (const __attribute__((address_space(1))) void*)(uintptr_t)g,
        (__attribute__((address_space(3))) void*)(uintptr_t)l,
        16, 0, 0);
}

enum { MM_QKV = 0, MM_RESID = 1, MM_GELU_BF16 = 2, MM_GELU_F32 = 3, MM_LAT = 4 };

// ---------------------------------------------------------------------------
// bf16 MFMA GEMM: 3-buffer pipeline, ONE barrier per K-iteration.
//   iter t: vmcnt(4) -> s_barrier -> STAGE(tile t+2) -> ds_read -> MFMA
// Safety without a 2nd barrier: buf[(t+2)%3] was read at iter t-1; each
// wave's ds_reads complete (reg data-dep -> compiler lgkmcnt) before it
// ARRIVES at barrier1@t, and the stager only passes barrier1@t after all
// waves arrive -> reads strictly precede the overwrite. vmcnt(4) at top
// drains tile t (issued early in iter t-2: ~2 iterations of latency cover)
// while tile t+1's 4 loads stay in flight. Stage-issue is off the MFMA tail.
// XCD-chunked block swizzle (contiguous row-panels per XCD), setprio on MFMA.
// 128x128 tile, BK=32, 4 waves x 64x64 subtile of 16x16x32 MFMA.
// LDS chunk p (16B) holds global chunk ((p&3)^((p>>3)&3)) of row p>>2;
// frag read position = quad ^ ((l16>>1)&3)  -> max 2 lanes/bank-group (free).
// Round-2 A/B: 3-buf/48KB (3 blk/CU) >> 2-buf/32KB (5 blk/CU): depth > occ.
// ---------------------------------------------------------------------------
__global__ __launch_bounds__(256) void mm_kernel(
    const u16* __restrict__ A, const u16* __restrict__ Bt,
    const float* __restrict__ bias, float* __restrict__ Cf, u16* __restrict__ Cb,
    const float* __restrict__ pe, int M, int N, int K, int mode, int gx)
{
    __shared__ __align__(16) u16 As[3 * 4096];
    __shared__ __align__(16) u16 Bs[3 * 4096];
    const int tid = threadIdx.x;

    // XCD-aware swizzle: HW dispatches block d to XCD d%8; remap so XCD k
    // owns logical blocks [k*cpx, (k+1)*cpx) -> contiguous row-panels/XCD.
    // All call sites have gridDim.x % 8 == 0 (bijective).
    const unsigned nwg = gridDim.x, cpx = nwg >> 3;
    const unsigned id = blockIdx.x;
    const unsigned swz = (id & 7u) * cpx + (id >> 3);
    const int bx = (int)(swz % (unsigned)gx);
    const int by = (int)(swz / (unsigned)gx);
    const int row0 = by * 128, col0 = bx * 128;

    const int lane = tid & 63, w = tid >> 6;
    const int m_w = (w & 1) << 6, n_w = (w >> 1) << 6;
    const int l16 = lane & 15, quad = lane >> 4;

    // staging source (chunk-permuted): this thread feeds LDS chunks tid, tid+256
    const int r0 = tid >> 2;
    const int seg = ((tid & 3) ^ ((tid >> 3) & 3)) << 3;   // permuted k-chunk, elems
    const u16* Ag0 = A + (size_t)(row0 + r0) * K + seg;
    const u16* Ag1 = A + (size_t)(row0 + r0 + 64) * K + seg;
    const u16* Bg0 = Bt + (size_t)(col0 + r0) * K + seg;
    const u16* Bg1 = Bt + (size_t)(col0 + r0 + 64) * K + seg;

    const int pos = (quad ^ ((l16 >> 1) & 3)) << 3;        // frag read chunk, elems

    facc4 acc[4][4] = {};
    const int iters = K >> 5;          // >= 8 for all call sites

    u16* Ald = As + w * 512;
    u16* Bld = Bs + w * 512;
    // prologue: stage tiles 0,1 into buffers 0,1 (8 loads in flight)
    #pragma unroll
    for (int pf = 0; pf < 2; ++pf) {
        const int ko = pf << 5;
        const int bo = pf << 12;
        gl_lds16(Ag0 + ko, Ald + bo);
        gl_lds16(Ag1 + ko, Ald + bo + 2048);
        gl_lds16(Bg0 + ko, Bld + bo);
        gl_lds16(Bg1 + ko, Bld + bo + 2048);
    }

    int b = 0;                               // buffer index = it % 3
    for (int it = 0; it < iters; ++it) {
        // drain tile `it` (issued ~2 iterations ago); keep tile it+1 in flight
        if (it + 1 < iters) asm volatile("s_waitcnt vmcnt(4)" ::: "memory");
        else                asm volatile("s_waitcnt vmcnt(0)" ::: "memory");
        __builtin_amdgcn_s_barrier();        // tile-it in LDS for all waves;
        asm volatile("" ::: "memory");       // also: all reads of buf (it+2)%3 done

        if (it + 2 < iters) {                // stage tile it+2 (earliest safe point)
            const int ko = (it + 2) << 5;
            const int bo = ((b == 0) ? 2 : b - 1) << 12;   // (it+2)%3
            gl_lds16(Ag0 + ko, Ald + bo);
            gl_lds16(Ag1 + ko, Ald + bo + 2048);
            gl_lds16(Bg0 + ko, Bld + bo);
            gl_lds16(Bg1 + ko, Bld + bo + 2048);
        }

        const u16* Ab = As + (b << 12);
        const u16* Bb = Bs + (b << 12);
        bfrag8 af[4], bf[4];
        #pragma unroll
        for (int i = 0; i < 4; ++i)
            af[i] = *(const bfrag8*)&Ab[(m_w + i * 16 + l16) * 32 + pos];
        #pragma unroll
        for (int j = 0; j < 4; ++j)
            bf[j] = *(const bfrag8*)&Bb[(n_w + j * 16 + l16) * 32 + pos];
        __builtin_amdgcn_s_setprio(1);
        #pragma unroll
        for (int i = 0; i < 4; ++i)
            #pragma unroll
            for (int j = 0; j < 4; ++j)
                acc[i][j] = __builtin_amdgcn_mfma_f32_16x16x32_bf16(
                    af[i], bf[j], acc[i][j], 0, 0, 0);
        __builtin_amdgcn_s_setprio(0);
        asm volatile("" ::: "memory");       // pin loop body below next barrier
        b = (b == 2) ? 0 : b + 1;
    }

    #pragma unroll
    for (int i = 0; i < 4; ++i) {
        #pragma unroll
        for (int r = 0; r < 4; ++r) {
            const int row = row0 + m_w + i * 16 + quad * 4 + r;
            #pragma unroll
            for (int j = 0; j < 4; ++j) {
                const int col = col0 + n_w + j * 16 + l16;
                float v = acc[i][j][r] + bias[col];
                const size_t idx = (size_t)row * N + col;
                if (mode == MM_QKV) {
                    Cb[idx] = f2bf(v);
                } else if (mode == MM_RESID) {
                    Cf[idx] += v;
                } else if (mode == MM_GELU_BF16) {
                    Cb[idx] = f2bf(gelu_f(v));
                } else if (mode == MM_GELU_F32) {
                    Cf[idx] = gelu_f(v);
                } else { // MM_LAT: gelu + precomputed positional encoding, dual out
                    v = gelu_f(v) + pe[col];
                    Cf[idx] = v;
                    Cb[idx] = f2bf(v);
                }
            }
        }
    }
}

// positional encoding table pe[s*512+d], 102400 entries
__global__ __launch_bounds__(256) void pe_kernel(float* __restrict__ pe)
{
    const int idx = blockIdx.x * 256 + threadIdx.x;
    const int s = idx >> 9, d = idx & 511;
    const float ang = (float)s * expf((float)(d & ~1) * (-9.2103403719761836f / 512.0f));
    pe[idx] = (d & 1) ? cosf(ang) : sinf(ang);
}

// ---------------------------------------------------------------------------
// MFMA attention. Grid (qtile=4, h=8, b=128); 4 waves; wave = 16 queries.
// ---------------------------------------------------------------------------
__global__ __launch_bounds__(256) void attn_kernel(
    const u16* __restrict__ qkv, const float* __restrict__ tb,
    u16* __restrict__ ctxb)
{
    const int qt = blockIdx.x, h = blockIdx.y, b = blockIdx.z;
    const int tid = threadIdx.x;
    const int w = tid >> 6, lane = tid & 63;
    const int l16 = lane & 15, quad = lane >> 4;

    __shared__ __align__(16) u16 kv[16896];        // Ks[208][64] / Vt[64][264]
    __shared__ __align__(16) u16 Ps[4][16][232];   // softmaxed P per wave

    const size_t rowbase = (size_t)b * SEQ;
    const int q0w = qt * 64 + w * 16;

    // stage K slice: 208 rows x 8 chunks; chunk position seg holds dims
    // ((seg^(key&7))*8..) via DMA source permutation -> conflict-free reads
    for (int g = w; g < 26; g += 4) {
        const int c = g * 64 + lane;
        const int key = c >> 3, seg = c & 7;
        const int krow = key < 200 ? key : 199;
        gl_lds16(qkv + (rowbase + krow) * QKVS + 512 + h * 64 +
                 ((seg ^ (key & 7)) << 3),
                 kv + g * 512);
    }
    int qrow = (int)rowbase + q0w + l16;
    if (qrow > ROWS - 1) qrow = ROWS - 1;
    const u16* qp = qkv + (size_t)qrow * QKVS + h * 64 + quad * 8;
    bfrag8 aq0 = *(const bfrag8*)(qp);
    bfrag8 aq1 = *(const bfrag8*)(qp + 32);
    __syncthreads();

    facc4 sc[13];
    #pragma unroll
    for (int nt = 0; nt < 13; ++nt) {
        const int key = nt * 16 + l16, kk = key & 7;
        bfrag8 b0 = *(const bfrag8*)&kv[key * 64 + ((quad ^ kk) << 3)];
        bfrag8 b1 = *(const bfrag8*)&kv[key * 64 + (((4 + quad) ^ kk) << 3)];
        facc4 a = {};
        a = __builtin_amdgcn_mfma_f32_16x16x32_bf16(aq0, b0, a, 0, 0, 0);
        a = __builtin_amdgcn_mfma_f32_16x16x32_bf16(aq1, b1, a, 0, 0, 0);
        sc[nt] = a;
    }
    __syncthreads();

    // stage V transposed: Vt[dk][VTS], col = key, zero keys >= 200
    for (int c = 0; c < 7; ++c) {
        const int key = c * 32 + (tid & 31);
        const int dkb = (tid >> 5) * 8;
        u16 vals[8];
        if (key < 200) {
            *(uint4*)vals = *(const uint4*)(qkv + (rowbase + key) * QKVS +
                                            1024 + h * 64 + dkb);
        } else {
            #pragma unroll
            for (int i = 0; i < 8; ++i) vals[i] = 0;
        }
        #pragma unroll
        for (int i = 0; i < 8; ++i)
            kv[(dkb + i) * VTS + key] = vals[i];
    }

    #pragma unroll
    for (int r = 0; r < 4; ++r) {
        const int i = q0w + quad * 4 + r;
        #pragma unroll
        for (int nt = 0; nt < 13; ++nt) {
            const int j = nt * 16 + l16;
            float s;
            if (j < 200) {
                const float tbv = (i < 200) ? tb[(h * 200 + i) * 200 + j] : 0.f;
                s = sc[nt][r] * 0.125f + tbv;
            } else s = -INFINITY;
            sc[nt][r] = s;
        }
        float m = sc[0][r];
        #pragma unroll
        for (int nt = 1; nt < 13; ++nt) m = fmaxf(m, sc[nt][r]);
        #pragma unroll
        for (int off = 8; off > 0; off >>= 1) m = fmaxf(m, __shfl_xor(m, off, 64));
        float ssum = 0.f;
        #pragma unroll
        for (int nt = 0; nt < 13; ++nt) {
            const float e = __expf(sc[nt][r] - m);
            sc[nt][r] = e; ssum += e;
        }
        #pragma unroll
        for (int off = 8; off > 0; off >>= 1) ssum += __shfl_xor(ssum, off, 64);
        const float inv = 1.0f / ssum;
        #pragma unroll
        for (int nt = 0; nt < 13; ++nt)
            Ps[w][quad * 4 + r][nt * 16 + l16] = f2bf(sc[nt][r] * inv);
        Ps[w][quad * 4 + r][208 + l16] = 0;
    }
    __syncthreads();

    facc4 pacc[4] = {};
    for (int ks = 0; ks < 7; ++ks) {
        bfrag8 ap = *(const bfrag8*)&Ps[w][l16][ks * 32 + quad * 8];
        #pragma unroll
        for (int nt = 0; nt < 4; ++nt) {
            const int dkrow = nt * 16 + l16;
            bfrag8 bv = *(const bfrag8*)&kv[dkrow * VTS + ks * 32 + quad * 8];
            pacc[nt] = __builtin_amdgcn_mfma_f32_16x16x32_bf16(ap, bv, pacc[nt], 0, 0, 0);
        }
    }

    #pragma unroll
    for (int r = 0; r < 4; ++r) {
        const int i = q0w + quad * 4 + r;
        if (i < 200) {
            #pragma unroll
            for (int nt = 0; nt < 4; ++nt)
                ctxb[(rowbase + i) * 512 + h * 64 + nt * 16 + l16] = f2bf(pacc[nt][r]);
        }
    }
}

// ---------------------------------------------------------------------------
// Transpose-convert W [K,N] fp32 -> Wt [N,K] bf16, batched over blockIdx.z
// ---------------------------------------------------------------------------
__global__ __launch_bounds__(256) void tconv_kernel(
    const float* __restrict__ W, u16* __restrict__ O, int K, int N,
    size_t wStride, size_t oStride)
{
    __shared__ u16 T[64][80];
    const float* Wz = W + wStride * blockIdx.z;
    u16* Oz = O + oStride * blockIdx.z;
    const int n0 = blockIdx.x * 64, k0 = blockIdx.y * 64, t = threadIdx.x;
    {
        const int kr = t >> 2, seg = t & 3;
        const float* wp = Wz + (size_t)(k0 + kr) * N + n0 + seg * 16;
        alignas(16) u16 tmp[16];
        #pragma unroll
        for (int q = 0; q < 4; ++q) {
            float4 f = ((const float4*)wp)[q];
            tmp[q * 4 + 0] = f2bf(f.x); tmp[q * 4 + 1] = f2bf(f.y);
            tmp[q * 4 + 2] = f2bf(f.z); tmp[q * 4 + 3] = f2bf(f.w);
        }
        *(uint4*)&T[kr][seg * 16]     = *(uint4*)&tmp[0];
        *(uint4*)&T[kr][seg * 16 + 8] = *(uint4*)&tmp[8];
    }
    __syncthreads();
    {
        const int n = t >> 2, kseg = t & 3;
        alignas(16) u16 o[16];
        #pragma unroll
        for (int i = 0; i < 16; ++i) o[i] = T[kseg * 16 + i][n];
        uint4* op = (uint4*)(Oz + (size_t)(n0 + n) * K + k0 + kseg * 16);
        op[0] = *(uint4*)&o[0];
        op[1] = *(uint4*)&o[8];
    }
}

// qkvo batch: z = layer*4 + {q,k,v,o}, all 512x512
__global__ __launch_bounds__(256) void tconv4_kernel(
    const float* __restrict__ Wq, const float* __restrict__ Wk,
    const float* __restrict__ Wv, const float* __restrict__ Wo,
    u16* __restrict__ Out)
{
    __shared__ u16 T[64][80];
    const int z = blockIdx.z, layer = z >> 2, m = z & 3;
    const float* W = (m == 0 ? Wq : m == 1 ? Wk : m == 2 ? Wv : Wo)
                     + (size_t)layer * 262144;
    u16* O = Out + (size_t)z * 262144;
    const int n0 = blockIdx.x * 64, k0 = blockIdx.y * 64, t = threadIdx.x;
    {
        const int kr = t >> 2, seg = t & 3;
        const float* wp = W + (size_t)(k0 + kr) * 512 + n0 + seg * 16;
        alignas(16) u16 tmp[16];
        #pragma unroll
        for (int q = 0; q < 4; ++q) {
            float4 f = ((const float4*)wp)[q];
            tmp[q * 4 + 0] = f2bf(f.x); tmp[q * 4 + 1] = f2bf(f.y);
            tmp[q * 4 + 2] = f2bf(f.z); tmp[q * 4 + 3] = f2bf(f.w);
        }
        *(uint4*)&T[kr][seg * 16]     = *(uint4*)&tmp[0];
        *(uint4*)&T[kr][seg * 16 + 8] = *(uint4*)&tmp[8];
    }
    __syncthreads();
    {
        const int n = t >> 2, kseg = t & 3;
        alignas(16) u16 o[16];
        #pragma unroll
        for (int i = 0; i < 16; ++i) o[i] = T[kseg * 16 + i][n];
        uint4* op = (uint4*)(O + (size_t)(n0 + n) * 512 + k0 + kseg * 16);
        op[0] = *(uint4*)&o[0];
        op[1] = *(uint4*)&o[8];
    }
}

// concat biases: bqkv[l][1536] = [bq[l] | bk[l] | bv[l]]
__global__ __launch_bounds__(256) void bqkv_kernel(
    const float* __restrict__ bq, const float* __restrict__ bk,
    const float* __restrict__ bv, float* __restrict__ o)
{
    const int l = blockIdx.x, t = threadIdx.x;
    for (int c = t; c < 1536; c += 256) {
        float v = (c < 512) ? bq[l * 512 + c]
                : (c < 1024) ? bk[l * 512 + c - 512]
                             : bv[l * 512 + c - 1024];
        o[l * 1536 + c] = v;
    }
}

// LayerNorm: 1 wave per row, 4 rows/block, vectorized, shuffle-only reduce
__global__ __launch_bounds__(256) void ln_kernel(
    float* __restrict__ x, const float* __restrict__ g,
    const float* __restrict__ bb, u16* __restrict__ xb)
{
    const int w = threadIdx.x >> 6, lane = threadIdx.x & 63;
    const size_t row = (size_t)blockIdx.x * 4 + w;
    float* xr = x + row * DMODEL;
    u16* xbr = xb + row * DMODEL;
    const int c = lane * 8;
    float4 a = *(const float4*)(xr + c);
    float4 b = *(const float4*)(xr + c + 4);
    float s = a.x + a.y + a.z + a.w + b.x + b.y + b.z + b.w;
    #pragma unroll
    for (int off = 32; off > 0; off >>= 1) s += __shfl_xor(s, off, 64);
    const float mu = s * (1.0f / 512.0f);
    a.x -= mu; a.y -= mu; a.z -= mu; a.w -= mu;
    b.x -= mu; b.y -= mu; b.z -= mu; b.w -= mu;
    float v = a.x * a.x + a.y * a.y + a.z * a.z + a.w * a.w
            + b.x * b.x + b.y * b.y + b.z * b.z + b.w * b.w;
    #pragma unroll
    for (int off = 32; off > 0; off >>= 1) v += __shfl_xor(v, off, 64);
    const float rstd = rsqrtf(v * (1.0f / 512.0f) + 1e-5f);
    float4 g0 = *(const float4*)(g + c), g1 = *(const float4*)(g + c + 4);
    float4 b0 = *(const float4*)(bb + c), b1 = *(const float4*)(bb + c + 4);
    float4 o0, o1;
    o0.x = a.x * rstd * g0.x + b0.x; o0.y = a.y * rstd * g0.y + b0.y;
    o0.z = a.z * rstd * g0.z + b0.z; o0.w = a.w * rstd * g0.w + b0.w;
    o1.x = b.x * rstd * g1.x + b1.x; o1.y = b.y * rstd * g1.y + b1.y;
    o1.z = b.z * rstd * g1.z + b1.z; o1.w = b.w * rstd * g1.w + b1.w;
    *(float4*)(xr + c) = o0;
    *(float4*)(xr + c + 4) = o1;
    alignas(16) u16 ob[8] = { f2bf(o0.x), f2bf(o0.y), f2bf(o0.z), f2bf(o0.w),
                              f2bf(o1.x), f2bf(o1.y), f2bf(o1.z), f2bf(o1.w) };
    *(uint4*)(xbr + c) = *(uint4*)ob;
}

__global__ __launch_bounds__(256) void concat_z_kernel(
    const float* __restrict__ zs, const float* __restrict__ zk, u16* __restrict__ z)
{
    const int b = blockIdx.x, t = threadIdx.x;
    z[b * 256 + t] = f2bf((t < 128) ? zs[b * 128 + t] : zk[b * 128 + t - 128]);
}

__global__ __launch_bounds__(64) void traj_head_kernel(
    const float* __restrict__ t1, const float* __restrict__ Wp2,
    const float* __restrict__ bp2, float* __restrict__ out)
{
    const int r = blockIdx.x, t = threadIdx.x;
    __shared__ float red[6][64];
    float p[6] = {};
    const float* tr = t1 + (size_t)r * 256;
    for (int kk = t; kk < 256; kk += 64) {
        float tv = tr[kk];
        #pragma unroll
        for (int c = 0; c < 6; ++c) p[c] = fmaf(tv, Wp2[kk * 6 + c], p[c]);
    }
    #pragma unroll
    for (int c = 0; c < 6; ++c) red[c][t] = p[c];
    __syncthreads();
    if (t < 6) {
        float a = 0.f;
        for (int j = 0; j < 64; ++j) a += red[t][j];
        out[(size_t)r * 6 + t] = a + bp2[t];
    }
}

__global__ __launch_bounds__(256) void sig_head_kernel(
    const float* __restrict__ zs, const float* __restrict__ zk,
    const float* __restrict__ Ws1, const float* __restrict__ bs1,
    const float* __restrict__ Ws2, const float* __restrict__ bs2,
    float* __restrict__ out)
{
    const int b = blockIdx.x, t = threadIdx.x;
    __shared__ float zrow[256];
    __shared__ float h1[256];
    zrow[t] = (t < 128) ? zs[b * 128 + t] : zk[b * 128 + t - 128];
    __syncthreads();
    float acc = bs1[t];
    for (int kk = 0; kk < 256; ++kk) acc = fmaf(zrow[kk], Ws1[kk * 256 + t], acc);
    h1[t] = gelu_f(acc);
    __syncthreads();
    if (t < 5) {
        float a = bs2[t];
        for (int kk = 0; kk < 256; ++kk) a = fmaf(h1[kk], Ws2[kk * 5 + t], a);
        out[b * 5 + t] = a;
    }
}

extern "C" void kernel_launch(void* const* d_in, const int* in_sizes, int n_in,
                              void* d_out, int out_size, void* d_ws, size_t ws_size,
                              hipStream_t stream) {
    const float* z_style   = (const float*)d_in[0];
    const float* z_skill   = (const float*)d_in[1];
    const float* W_lat     = (const float*)d_in[2];
    const float* b_lat     = (const float*)d_in[3];
    const float* temp_bias = (const float*)d_in[4];
    const float* Wq  = (const float*)d_in[5];
    const float* bq  = (const float*)d_in[6];
    const float* Wk  = (const float*)d_in[7];
    const float* bk  = (const float*)d_in[8];
    const float* Wv  = (const float*)d_in[9];
    const float* bv  = (const float*)d_in[10];
    const float* Wo  = (const float*)d_in[11];
    const float* bo  = (const float*)d_in[12];
    const float* g1  = (const float*)d_in[13];
    const float* be1 = (const float*)d_in[14];
    const float* g2  = (const float*)d_in[15];
    const float* be2 = (const float*)d_in[16];
    const float* W1  = (const float*)d_in[17];
    const float* bf1 = (const float*)d_in[18];
    const float* W2  = (const float*)d_in[19];
    const float* bf2 = (const float*)d_in[20];
    const float* Wp1 = (const float*)d_in[21];
    const float* bp1 = (const float*)d_in[22];
    const float* Wp2 = (const float*)d_in[23];
    const float* bp2 = (const float*)d_in[24];
    const float* Ws1 = (const float*)d_in[25];
    const float* bs1 = (const float*)d_in[26];
    const float* Ws2 = (const float*)d_in[27];
    const float* bs2 = (const float*)d_in[28];
    float* out = (float*)d_out;

    // ---- workspace layout (bytes), total ~222.1 MB ----
    char* Wb = (char*)d_ws;
    float* x     = (float*)(Wb + 0);             // [25600,512] fp32 residual
    u16*  xb     = (u16*)(Wb + 52428800);        // [25600,512] bf16 (LN out)
    u16*  qkv    = (u16*)(Wb + 78643200);        // [25600,1536] bf16
    u16*  cx     = (u16*)(Wb + 157286400);       // ctx bf16 [25600,512]
    u16*  ff1b   = (u16*)(Wb + 78643200);        // [25600,2048] overlays qkv+cx
    u16*  wlatT  = (u16*)(Wb + 78643200);        // [102400,256] pre-loop only
    float* t1    = (float*)(Wb + 157286400);     // head scratch (cx dead)
    u16*  qkvoT  = (u16*)(Wb + 183500800);       // 24 x [512,512]
    u16*  w1T    = (u16*)(Wb + 196083712);       // 6 x [2048,512]
    u16*  w2T    = (u16*)(Wb + 208666624);       // 6 x [512,2048]
    u16*  wp1T   = (u16*)(Wb + 221249536);       // [256,512]
    float* bqkv  = (float*)(Wb + 221511680);     // [6,1536]
    u16*  zbb    = (u16*)(Wb + 221548544);       // [128,256]
    float* pe    = (float*)(Wb + 221614080);     // [102400] fp32 PE table

    // ---- weight conversion (every launch; inputs restored each call) ----
    tconv4_kernel<<<dim3(8, 8, 24), 256, 0, stream>>>(Wq, Wk, Wv, Wo, qkvoT);
    tconv_kernel<<<dim3(32, 8, 6), 256, 0, stream>>>(W1, w1T, DMODEL, DFF,
                                                     (size_t)DMODEL * DFF, (size_t)DMODEL * DFF);
    tconv_kernel<<<dim3(8, 32, 6), 256, 0, stream>>>(W2, w2T, DFF, DMODEL,
                                                     (size_t)DMODEL * DFF, (size_t)DMODEL * DFF);
    tconv_kernel<<<dim3(1600, 4, 1), 256, 0, stream>>>(W_lat, wlatT, LATDIM, DMODEL * SEQ, 0, 0);
    tconv_kernel<<<dim3(4, 8, 1), 256, 0, stream>>>(Wp1, wp1T, DMODEL, 256, 0, 0);
    bqkv_kernel<<<NLAYER, 256, 0, stream>>>(bq, bk, bv, bqkv);
    concat_z_kernel<<<BATCH, 256, 0, stream>>>(z_style, z_skill, zbb);
    pe_kernel<<<400, 256, 0, stream>>>(pe);

    // x = gelu(z @ W_lat + b_lat) + pe  (dual fp32/bf16)
    mm_kernel<<<dim3(800), 256, 0, stream>>>(
        zbb, wlatT, b_lat, x, xb, pe, BATCH, DMODEL * SEQ, LATDIM, MM_LAT, 800);

    for (int l = 0; l < NLAYER; ++l) {
        mm_kernel<<<dim3(12 * 200), 256, 0, stream>>>(
            xb, qkvoT + (size_t)l * 4 * 262144, bqkv + l * 1536, nullptr, qkv, pe,
            ROWS, QKVS, DMODEL, MM_QKV, 12);
        attn_kernel<<<dim3(4, NHEAD, BATCH), 256, 0, stream>>>(qkv, temp_bias, cx);
        mm_kernel<<<dim3(4 * 200), 256, 0, stream>>>(
            cx, qkvoT + (size_t)(l * 4 + 3) * 262144, bo + l * DMODEL, x, nullptr, pe,
            ROWS, DMODEL, DMODEL, MM_RESID, 4);
        ln_kernel<<<ROWS / 4, 256, 0, stream>>>(x, g1 + l * DMODEL, be1 + l * DMODEL, xb);
        mm_kernel<<<dim3(16 * 200), 256, 0, stream>>>(
            xb, w1T + (size_t)l * DMODEL * DFF, bf1 + l * DFF, nullptr, ff1b, pe,
            ROWS, DFF, DMODEL, MM_GELU_BF16, 16);
        mm_kernel<<<dim3(4 * 200), 256, 0, stream>>>(
            ff1b, w2T + (size_t)l * DMODEL * DFF, bf2 + l * DMODEL, x, nullptr, pe,
            ROWS, DMODEL, DFF, MM_RESID, 4);
        ln_kernel<<<ROWS / 4, 256, 0, stream>>>(x, g2 + l * DMODEL, be2 + l * DMODEL, xb);
    }

    // heads
    mm_kernel<<<dim3(2 * 200), 256, 0, stream>>>(
        xb, wp1T, bp1, t1, nullptr, pe, ROWS, 256, DMODEL, MM_GELU_F32, 2);
    traj_head_kernel<<<ROWS, 64, 0, stream>>>(t1, Wp2, bp2, out);
    sig_head_kernel<<<BATCH, 256, 0, stream>>>(z_style, z_skill, Ws1, bs1, Ws2, bs2,
                                               out + (size_t)ROWS * OUTDIM);
}

// Round 5
// 3113.197 us; speedup vs baseline: 1.0287x; 1.0287x over previous
//
#include <hip/hip_runtime.h>
#include <math.h>

#define BATCH 128
#define DMODEL 512
#define NHEAD 8
#define NLAYER 6
#define SEQ 200
#define LATDIM 256
#define OUTDIM 6
#define DFF 2048
#define ROWS (BATCH * SEQ)   // 25600
#define QKVS 1536            // fused qkv row stride
#define VTS 264              // Vt row stride (u16): 528B, bank-rotating

typedef unsigned short u16;
typedef __attribute__((ext_vector_type(8))) short bfrag8;
typedef __attribute__((ext_vector_type(4))) float facc4;

// branch-free erf (Abramowitz-Stegun 7.1.26, |err| <= 1.5e-7) -> cheap exact-gelu
__device__ __forceinline__ float gelu_f(float v) {
    const float x = v * 0.70710678118654752f;
    const float ax = fabsf(x);
    const float t = __builtin_amdgcn_rcpf(fmaf(0.3275911f, ax, 1.0f));
    float p = fmaf(1.061405429f, t, -1.453152027f);
    p = fmaf(p, t, 1.421413741f);
    p = fmaf(p, t, -0.284496736f);
    p = fmaf(p, t, 0.254829592f);
    p = p * t;
    const float e = __expf(-ax * ax);
    float er = fmaf(-p, e, 1.0f);          // erf(|x|)
    er = copysignf(er, x);
    return 0.5f * v * (1.0f + er);
}
__device__ __forceinline__ u16 f2bf(float f) {
    unsigned u = __float_as_uint(f);
    u += 0x7fffu + ((u >> 16) & 1u);
    return (u16)(u >> 16);
}
// async global->LDS, 16B per lane; HW dest = wave-uniform base + lane*16
__device__ __forceinline__ void gl_lds16(const u16* g, u16* l) {
    __builtin_amdgcn_global_load_lds(
        (const __attribute__((address_space(1))) void*)(uintptr_t)g,
        (__attribute__((address_space(3))) void*)(uintptr_t)l,
        16, 0, 0);
}

enum { MM_QKV = 0, MM_RESID = 1, MM_GELU_BF16 = 2, MM_GELU_F32 = 3, MM_LAT = 4 };

// ---------------------------------------------------------------------------
// bf16 MFMA GEMM (round-3 structure, restored): 3-stage global_load_lds
// pipeline, counted vmcnt (steady vmcnt(8): 12 loads / 3 tiles in flight),
// two barriers/iter, XCD-chunked swizzle, setprio on MFMA cluster.
// 128x128 tile, BK=32, 4 waves x 64x64 subtile of 16x16x32 MFMA.
// LDS chunk p (16B) holds global chunk ((p&3)^((p>>3)&3)) of row p>>2;
// frag read position = quad ^ ((l16>>1)&3)  -> max 2 lanes/bank-group (free).
// Depth evidence: 12-in-flight (r1/r3) FF1=113-124us; 8-in-flight (r0/r2/r4)
// FF1=158-161us. Depth-3 is required; single-barrier depth-2 (r4) regressed.
// ---------------------------------------------------------------------------
__global__ __launch_bounds__(256) void mm_kernel(
    const u16* __restrict__ A, const u16* __restrict__ Bt,
    const float* __restrict__ bias, float* __restrict__ Cf, u16* __restrict__ Cb,
    const float* __restrict__ pe, int M, int N, int K, int mode, int gx)
{
    __shared__ __align__(16) u16 As[3 * 4096];
    __shared__ __align__(16) u16 Bs[3 * 4096];
    const int tid = threadIdx.x;

    const unsigned nwg = gridDim.x, cpx = nwg >> 3;
    const unsigned id = blockIdx.x;
    const unsigned swz = (id & 7u) * cpx + (id >> 3);
    const int bx = (int)(swz % (unsigned)gx);
    const int by = (int)(swz / (unsigned)gx);
    const int row0 = by * 128, col0 = bx * 128;

    const int lane = tid & 63, w = tid >> 6;
    const int m_w = (w & 1) << 6, n_w = (w >> 1) << 6;
    const int l16 = lane & 15, quad = lane >> 4;

    const int r0 = tid >> 2;
    const int seg = ((tid & 3) ^ ((tid >> 3) & 3)) << 3;   // permuted k-chunk, elems
    const u16* Ag0 = A + (size_t)(row0 + r0) * K + seg;
    const u16* Ag1 = A + (size_t)(row0 + r0 + 64) * K + seg;
    const u16* Bg0 = Bt + (size_t)(col0 + r0) * K + seg;
    const u16* Bg1 = Bt + (size_t)(col0 + r0 + 64) * K + seg;

    const int pos = (quad ^ ((l16 >> 1) & 3)) << 3;        // frag read chunk, elems

    facc4 acc[4][4] = {};
    const int iters = K >> 5;          // >= 8 for all call sites

    u16* Ald = As + w * 512;
    u16* Bld = Bs + w * 512;
    #pragma unroll
    for (int pf = 0; pf < 3; ++pf) {
        const int ko = pf << 5;
        const int bo = pf << 12;
        gl_lds16(Ag0 + ko, Ald + bo);
        gl_lds16(Ag1 + ko, Ald + bo + 2048);
        gl_lds16(Bg0 + ko, Bld + bo);
        gl_lds16(Bg1 + ko, Bld + bo + 2048);
    }

    int b = 0;
    for (int it = 0; it < iters; ++it) {
        const int ahead = iters - 1 - it;
        if (ahead >= 2)      asm volatile("s_waitcnt vmcnt(8)" ::: "memory");
        else if (ahead == 1) asm volatile("s_waitcnt vmcnt(4)" ::: "memory");
        else                 asm volatile("s_waitcnt vmcnt(0)" ::: "memory");
        __builtin_amdgcn_s_barrier();           // all waves' tile-it loads done
        asm volatile("" ::: "memory");          // pin ds_reads below barrier

        const u16* Ab = As + (b << 12);
        const u16* Bb = Bs + (b << 12);
        bfrag8 af[4], bf[4];
        #pragma unroll
        for (int i = 0; i < 4; ++i)
            af[i] = *(const bfrag8*)&Ab[(m_w + i * 16 + l16) * 32 + pos];
        #pragma unroll
        for (int j = 0; j < 4; ++j)
            bf[j] = *(const bfrag8*)&Bb[(n_w + j * 16 + l16) * 32 + pos];
        __builtin_amdgcn_s_setprio(1);
        #pragma unroll
        for (int i = 0; i < 4; ++i)
            #pragma unroll
            for (int j = 0; j < 4; ++j)
                acc[i][j] = __builtin_amdgcn_mfma_f32_16x16x32_bf16(
                    af[i], bf[j], acc[i][j], 0, 0, 0);
        __builtin_amdgcn_s_setprio(0);

        // fence: MFMAs (and thus their lgkm drains) complete before barrier,
        // so no wave can overwrite buf b while another still reads it (rule 18)
        __builtin_amdgcn_sched_barrier(0);
        asm volatile("" ::: "memory");
        __builtin_amdgcn_s_barrier();
        asm volatile("" ::: "memory");

        if (it + 3 < iters) {                   // refill just-consumed buffer
            const int ko = (it + 3) << 5;
            const int bo = b << 12;
            gl_lds16(Ag0 + ko, Ald + bo);
            gl_lds16(Ag1 + ko, Ald + bo + 2048);
            gl_lds16(Bg0 + ko, Bld + bo);
            gl_lds16(Bg1 + ko, Bld + bo + 2048);
        }
        b = (b == 2) ? 0 : b + 1;
    }

    #pragma unroll
    for (int i = 0; i < 4; ++i) {
        #pragma unroll
        for (int r = 0; r < 4; ++r) {
            const int row = row0 + m_w + i * 16 + quad * 4 + r;
            #pragma unroll
            for (int j = 0; j < 4; ++j) {
                const int col = col0 + n_w + j * 16 + l16;
                float v = acc[i][j][r] + bias[col];
                const size_t idx = (size_t)row * N + col;
                if (mode == MM_QKV) {
                    Cb[idx] = f2bf(v);
                } else if (mode == MM_RESID) {
                    Cf[idx] += v;
                } else if (mode == MM_GELU_BF16) {
                    Cb[idx] = f2bf(gelu_f(v));
                } else if (mode == MM_GELU_F32) {
                    Cf[idx] = gelu_f(v);
                } else { // MM_LAT: gelu + precomputed positional encoding, dual out
                    v = gelu_f(v) + pe[col];
                    Cf[idx] = v;
                    Cb[idx] = f2bf(v);
                }
            }
        }
    }
}

// ---------------------------------------------------------------------------
// 256x128-tile variant for short-K wide-N GEMMs (QKV, FF1; K=512).
// 8 waves (512 threads), wave grid 4Mx2N, each wave the SAME proven 64x64
// subtile. Halves block count (half the prologue/epilogue generations),
// stages B once per 256 rows (3 loads/thread/iter for 2x MFMA), LDS
// 72KB -> 2 blocks/CU = 16 waves/CU. Same r3 two-barrier depth-3 pipeline
// (9 loads / 3 tiles in flight, steady vmcnt(6)). Same chunk permutation:
// seg = (p&3)^((p>>3)&3) depends only on (row parity pair), so the frag
// read XOR (quad ^ ((l16>>1)&3)) cancels identically for any 16-aligned
// row base -> lane reads k-seg quad, 0 bank conflicts (unchanged algebra).
// ---------------------------------------------------------------------------
__global__ __launch_bounds__(512) void mm256_kernel(
    const u16* __restrict__ A, const u16* __restrict__ Bt,
    const float* __restrict__ bias, u16* __restrict__ Cb,
    int N, int K, int mode, int gx)
{
    __shared__ __align__(16) u16 As[3 * 8192];   // 256 rows x 32 elems / buf
    __shared__ __align__(16) u16 Bs[3 * 4096];   // 128 rows x 32 elems / buf
    const int tid = threadIdx.x;

    const unsigned nwg = gridDim.x, cpx = nwg >> 3;
    const unsigned id = blockIdx.x;
    const unsigned swz = (id & 7u) * cpx + (id >> 3);
    const int bx = (int)(swz % (unsigned)gx);
    const int by = (int)(swz / (unsigned)gx);
    const int row0 = by * 256, col0 = bx * 128;

    const int lane = tid & 63, w = tid >> 6;
    const int m_w = (w & 3) << 6, n_w = (w >> 2) << 6;
    const int l16 = lane & 15, quad = lane >> 4;

    // A chunks 0..1023: thread t feeds chunks t (rows 0..127) and t+512
    // (rows 128..255); B chunks 0..511: thread t feeds chunk t. seg formula
    // invariant under +512 chunk offset (512>>3 & 3 == 0).
    const int r0 = tid >> 2;                               // 0..127
    const int seg = ((tid & 3) ^ ((tid >> 3) & 3)) << 3;
    const u16* Ag0 = A + (size_t)(row0 + r0) * K + seg;
    const u16* Ag1 = A + (size_t)(row0 + r0 + 128) * K + seg;
    const u16* Bg0 = Bt + (size_t)(col0 + r0) * K + seg;

    const int pos = (quad ^ ((l16 >> 1) & 3)) << 3;

    facc4 acc[4][4] = {};
    const int iters = K >> 5;          // 16 for K=512

    u16* Ald = As + w * 512;           // wave-slice DMA bases (64 chunks/wave)
    u16* Bld = Bs + w * 512;
    #pragma unroll
    for (int pf = 0; pf < 3; ++pf) {
        const int ko = pf << 5;
        gl_lds16(Ag0 + ko, Ald + pf * 8192);
        gl_lds16(Ag1 + ko, Ald + pf * 8192 + 4096);
        gl_lds16(Bg0 + ko, Bld + pf * 4096);
    }

    int b = 0;
    for (int it = 0; it < iters; ++it) {
        const int ahead = iters - 1 - it;   // 3 loads per tile per thread
        if (ahead >= 2)      asm volatile("s_waitcnt vmcnt(6)" ::: "memory");
        else if (ahead == 1) asm volatile("s_waitcnt vmcnt(3)" ::: "memory");
        else                 asm volatile("s_waitcnt vmcnt(0)" ::: "memory");
        __builtin_amdgcn_s_barrier();
        asm volatile("" ::: "memory");

        const u16* Ab = As + b * 8192;
        const u16* Bb = Bs + b * 4096;
        bfrag8 af[4], bf[4];
        #pragma unroll
        for (int i = 0; i < 4; ++i)
            af[i] = *(const bfrag8*)&Ab[(m_w + i * 16 + l16) * 32 + pos];
        #pragma unroll
        for (int j = 0; j < 4; ++j)
            bf[j] = *(const bfrag8*)&Bb[(n_w + j * 16 + l16) * 32 + pos];
        __builtin_amdgcn_s_setprio(1);
        #pragma unroll
        for (int i = 0; i < 4; ++i)
            #pragma unroll
            for (int j = 0; j < 4; ++j)
                acc[i][j] = __builtin_amdgcn_mfma_f32_16x16x32_bf16(
                    af[i], bf[j], acc[i][j], 0, 0, 0);
        __builtin_amdgcn_s_setprio(0);

        __builtin_amdgcn_sched_barrier(0);
        asm volatile("" ::: "memory");
        __builtin_amdgcn_s_barrier();
        asm volatile("" ::: "memory");

        if (it + 3 < iters) {
            const int ko = (it + 3) << 5;
            gl_lds16(Ag0 + ko, Ald + b * 8192);
            gl_lds16(Ag1 + ko, Ald + b * 8192 + 4096);
            gl_lds16(Bg0 + ko, Bld + b * 4096);
        }
        b = (b == 2) ? 0 : b + 1;
    }

    #pragma unroll
    for (int i = 0; i < 4; ++i) {
        #pragma unroll
        for (int r = 0; r < 4; ++r) {
            const int row = row0 + m_w + i * 16 + quad * 4 + r;
            #pragma unroll
            for (int j = 0; j < 4; ++j) {
                const int col = col0 + n_w + j * 16 + l16;
                float v = acc[i][j][r] + bias[col];
                const size_t idx = (size_t)row * N + col;
                if (mode == MM_QKV) Cb[idx] = f2bf(v);
                else                Cb[idx] = f2bf(gelu_f(v));   // MM_GELU_BF16
            }
        }
    }
}

// positional encoding table pe[s*512+d], 102400 entries
__global__ __launch_bounds__(256) void pe_kernel(float* __restrict__ pe)
{
    const int idx = blockIdx.x * 256 + threadIdx.x;
    const int s = idx >> 9, d = idx & 511;
    const float ang = (float)s * expf((float)(d & ~1) * (-9.2103403719761836f / 512.0f));
    pe[idx] = (d & 1) ? cosf(ang) : sinf(ang);
}

// ---------------------------------------------------------------------------
// MFMA attention. Grid (qtile=4, h=8, b=128); 4 waves; wave = 16 queries.
// ---------------------------------------------------------------------------
__global__ __launch_bounds__(256) void attn_kernel(
    const u16* __restrict__ qkv, const float* __restrict__ tb,
    u16* __restrict__ ctxb)
{
    const int qt = blockIdx.x, h = blockIdx.y, b = blockIdx.z;
    const int tid = threadIdx.x;
    const int w = tid >> 6, lane = tid & 63;
    const int l16 = lane & 15, quad = lane >> 4;

    __shared__ __align__(16) u16 kv[16896];        // Ks[208][64] / Vt[64][264]
    __shared__ __align__(16) u16 Ps[4][16][232];   // softmaxed P per wave

    const size_t rowbase = (size_t)b * SEQ;
    const int q0w = qt * 64 + w * 16;

    for (int g = w; g < 26; g += 4) {
        const int c = g * 64 + lane;
        const int key = c >> 3, seg = c & 7;
        const int krow = key < 200 ? key : 199;
        gl_lds16(qkv + (rowbase + krow) * QKVS + 512 + h * 64 +
                 ((seg ^ (key & 7)) << 3),
                 kv + g * 512);
    }
    int qrow = (int)rowbase + q0w + l16;
    if (qrow > ROWS - 1) qrow = ROWS - 1;
    const u16* qp = qkv + (size_t)qrow * QKVS + h * 64 + quad * 8;
    bfrag8 aq0 = *(const bfrag8*)(qp);
    bfrag8 aq1 = *(const bfrag8*)(qp + 32);
    __syncthreads();

    facc4 sc[13];
    #pragma unroll
    for (int nt = 0; nt < 13; ++nt) {
        const int key = nt * 16 + l16, kk = key & 7;
        bfrag8 b0 = *(const bfrag8*)&kv[key * 64 + ((quad ^ kk) << 3)];
        bfrag8 b1 = *(const bfrag8*)&kv[key * 64 + (((4 + quad) ^ kk) << 3)];
        facc4 a = {};
        a = __builtin_amdgcn_mfma_f32_16x16x32_bf16(aq0, b0, a, 0, 0, 0);
        a = __builtin_amdgcn_mfma_f32_16x16x32_bf16(aq1, b1, a, 0, 0, 0);
        sc[nt] = a;
    }
    __syncthreads();

    for (int c = 0; c < 7; ++c) {
        const int key = c * 32 + (tid & 31);
        const int dkb = (tid >> 5) * 8;
        u16 vals[8];
        if (key < 200) {
            *(uint4*)vals = *(const uint4*)(qkv + (rowbase + key) * QKVS +
                                            1024 + h * 64 + dkb);
        } else {
            #pragma unroll
            for (int i = 0; i < 8; ++i) vals[i] = 0;
        }
        #pragma unroll
        for (int i = 0; i < 8; ++i)
            kv[(dkb + i) * VTS + key] = vals[i];
    }

    #pragma unroll
    for (int r = 0; r < 4; ++r) {
        const int i = q0w + quad * 4 + r;
        #pragma unroll
        for (int nt = 0; nt < 13; ++nt) {
            const int j = nt * 16 + l16;
            float s;
            if (j < 200) {
                const float tbv = (i < 200) ? tb[(h * 200 + i) * 200 + j] : 0.f;
                s = sc[nt][r] * 0.125f + tbv;
            } else s = -INFINITY;
            sc[nt][r] = s;
        }
        float m = sc[0][r];
        #pragma unroll
        for (int nt = 1; nt < 13; ++nt) m = fmaxf(m, sc[nt][r]);
        #pragma unroll
        for (int off = 8; off > 0; off >>= 1) m = fmaxf(m, __shfl_xor(m, off, 64));
        float ssum = 0.f;
        #pragma unroll
        for (int nt = 0; nt < 13; ++nt) {
            const float e = __expf(sc[nt][r] - m);
            sc[nt][r] = e; ssum += e;
        }
        #pragma unroll
        for (int off = 8; off > 0; off >>= 1) ssum += __shfl_xor(ssum, off, 64);
        const float inv = 1.0f / ssum;
        #pragma unroll
        for (int nt = 0; nt < 13; ++nt)
            Ps[w][quad * 4 + r][nt * 16 + l16] = f2bf(sc[nt][r] * inv);
        Ps[w][quad * 4 + r][208 + l16] = 0;
    }
    __syncthreads();

    facc4 pacc[4] = {};
    for (int ks = 0; ks < 7; ++ks) {
        bfrag8 ap = *(const bfrag8*)&Ps[w][l16][ks * 32 + quad * 8];
        #pragma unroll
        for (int nt = 0; nt < 4; ++nt) {
            const int dkrow = nt * 16 + l16;
            bfrag8 bv = *(const bfrag8*)&kv[dkrow * VTS + ks * 32 + quad * 8];
            pacc[nt] = __builtin_amdgcn_mfma_f32_16x16x32_bf16(ap, bv, pacc[nt], 0, 0, 0);
        }
    }

    #pragma unroll
    for (int r = 0; r < 4; ++r) {
        const int i = q0w + quad * 4 + r;
        if (i < 200) {
            #pragma unroll
            for (int nt = 0; nt < 4; ++nt)
                ctxb[(rowbase + i) * 512 + h * 64 + nt * 16 + l16] = f2bf(pacc[nt][r]);
        }
    }
}

// ---------------------------------------------------------------------------
// Transpose-convert W [K,N] fp32 -> Wt [N,K] bf16, batched over blockIdx.z
// ---------------------------------------------------------------------------
__global__ __launch_bounds__(256) void tconv_kernel(
    const float* __restrict__ W, u16* __restrict__ O, int K, int N,
    size_t wStride, size_t oStride)
{
    __shared__ u16 T[64][80];
    const float* Wz = W + wStride * blockIdx.z;
    u16* Oz = O + oStride * blockIdx.z;
    const int n0 = blockIdx.x * 64, k0 = blockIdx.y * 64, t = threadIdx.x;
    {
        const int kr = t >> 2, seg = t & 3;
        const float* wp = Wz + (size_t)(k0 + kr) * N + n0 + seg * 16;
        alignas(16) u16 tmp[16];
        #pragma unroll
        for (int q = 0; q < 4; ++q) {
            float4 f = ((const float4*)wp)[q];
            tmp[q * 4 + 0] = f2bf(f.x); tmp[q * 4 + 1] = f2bf(f.y);
            tmp[q * 4 + 2] = f2bf(f.z); tmp[q * 4 + 3] = f2bf(f.w);
        }
        *(uint4*)&T[kr][seg * 16]     = *(uint4*)&tmp[0];
        *(uint4*)&T[kr][seg * 16 + 8] = *(uint4*)&tmp[8];
    }
    __syncthreads();
    {
        const int n = t >> 2, kseg = t & 3;
        alignas(16) u16 o[16];
        #pragma unroll
        for (int i = 0; i < 16; ++i) o[i] = T[kseg * 16 + i][n];
        uint4* op = (uint4*)(Oz + (size_t)(n0 + n) * K + k0 + kseg * 16);
        op[0] = *(uint4*)&o[0];
        op[1] = *(uint4*)&o[8];
    }
}

// qkvo batch: z = layer*4 + {q,k,v,o}, all 512x512
__global__ __launch_bounds__(256) void tconv4_kernel(
    const float* __restrict__ Wq, const float* __restrict__ Wk,
    const float* __restrict__ Wv, const float* __restrict__ Wo,
    u16* __restrict__ Out)
{
    __shared__ u16 T[64][80];
    const int z = blockIdx.z, layer = z >> 2, m = z & 3;
    const float* W = (m == 0 ? Wq : m == 1 ? Wk : m == 2 ? Wv : Wo)
                     + (size_t)layer * 262144;
    u16* O = Out + (size_t)z * 262144;
    const int n0 = blockIdx.x * 64, k0 = blockIdx.y * 64, t = threadIdx.x;
    {
        const int kr = t >> 2, seg = t & 3;
        const float* wp = W + (size_t)(k0 + kr) * 512 + n0 + seg * 16;
        alignas(16) u16 tmp[16];
        #pragma unroll
        for (int q = 0; q < 4; ++q) {
            float4 f = ((const float4*)wp)[q];
            tmp[q * 4 + 0] = f2bf(f.x); tmp[q * 4 + 1] = f2bf(f.y);
            tmp[q * 4 + 2] = f2bf(f.z); tmp[q * 4 + 3] = f2bf(f.w);
        }
        *(uint4*)&T[kr][seg * 16]     = *(uint4*)&tmp[0];
        *(uint4*)&T[kr][seg * 16 + 8] = *(uint4*)&tmp[8];
    }
    __syncthreads();
    {
        const int n = t >> 2, kseg = t & 3;
        alignas(16) u16 o[16];
        #pragma unroll
        for (int i = 0; i < 16; ++i) o[i] = T[kseg * 16 + i][n];
        uint4* op = (uint4*)(O + (size_t)(n0 + n) * 512 + k0 + kseg * 16);
        op[0] = *(uint4*)&o[0];
        op[1] = *(uint4*)&o[8];
    }
}

// concat biases: bqkv[l][1536] = [bq[l] | bk[l] | bv[l]]
__global__ __launch_bounds__(256) void bqkv_kernel(
    const float* __restrict__ bq, const float* __restrict__ bk,
    const float* __restrict__ bv, float* __restrict__ o)
{
    const int l = blockIdx.x, t = threadIdx.x;
    for (int c = t; c < 1536; c += 256) {
        float v = (c < 512) ? bq[l * 512 + c]
                : (c < 1024) ? bk[l * 512 + c - 512]
                             : bv[l * 512 + c - 1024];
        o[l * 1536 + c] = v;
    }
}

// LayerNorm: 1 wave per row, 4 rows/block, vectorized, shuffle-only reduce
__global__ __launch_bounds__(256) void ln_kernel(
    float* __restrict__ x, const float* __restrict__ g,
    const float* __restrict__ bb, u16* __restrict__ xb)
{
    const int w = threadIdx.x >> 6, lane = threadIdx.x & 63;
    const size_t row = (size_t)blockIdx.x * 4 + w;
    float* xr = x + row * DMODEL;
    u16* xbr = xb + row * DMODEL;
    const int c = lane * 8;
    float4 a = *(const float4*)(xr + c);
    float4 b = *(const float4*)(xr + c + 4);
    float s = a.x + a.y + a.z + a.w + b.x + b.y + b.z + b.w;
    #pragma unroll
    for (int off = 32; off > 0; off >>= 1) s += __shfl_xor(s, off, 64);
    const float mu = s * (1.0f / 512.0f);
    a.x -= mu; a.y -= mu; a.z -= mu; a.w -= mu;
    b.x -= mu; b.y -= mu; b.z -= mu; b.w -= mu;
    float v = a.x * a.x + a.y * a.y + a.z * a.z + a.w * a.w
            + b.x * b.x + b.y * b.y + b.z * b.z + b.w * b.w;
    #pragma unroll
    for (int off = 32; off > 0; off >>= 1) v += __shfl_xor(v, off, 64);
    const float rstd = rsqrtf(v * (1.0f / 512.0f) + 1e-5f);
    float4 g0 = *(const float4*)(g + c), g1 = *(const float4*)(g + c + 4);
    float4 b0 = *(const float4*)(bb + c), b1 = *(const float4*)(bb + c + 4);
    float4 o0, o1;
    o0.x = a.x * rstd * g0.x + b0.x; o0.y = a.y * rstd * g0.y + b0.y;
    o0.z = a.z * rstd * g0.z + b0.z; o0.w = a.w * rstd * g0.w + b0.w;
    o1.x = b.x * rstd * g1.x + b1.x; o1.y = b.y * rstd * g1.y + b1.y;
    o1.z = b.z * rstd * g1.z + b1.z; o1.w = b.w * rstd * g1.w + b1.w;
    *(float4*)(xr + c) = o0;
    *(float4*)(xr + c + 4) = o1;
    alignas(16) u16 ob[8] = { f2bf(o0.x), f2bf(o0.y), f2bf(o0.z), f2bf(o0.w),
                              f2bf(o1.x), f2bf(o1.y), f2bf(o1.z), f2bf(o1.w) };
    *(uint4*)(xbr + c) = *(uint4*)ob;
}

__global__ __launch_bounds__(256) void concat_z_kernel(
    const float* __restrict__ zs, const float* __restrict__ zk, u16* __restrict__ z)
{
    const int b = blockIdx.x, t = threadIdx.x;
    z[b * 256 + t] = f2bf((t < 128) ? zs[b * 128 + t] : zk[b * 128 + t - 128]);
}

__global__ __launch_bounds__(64) void traj_head_kernel(
    const float* __restrict__ t1, const float* __restrict__ Wp2,
    const float* __restrict__ bp2, float* __restrict__ out)
{
    const int r = blockIdx.x, t = threadIdx.x;
    __shared__ float red[6][64];
    float p[6] = {};
    const float* tr = t1 + (size_t)r * 256;
    for (int kk = t; kk < 256; kk += 64) {
        float tv = tr[kk];
        #pragma unroll
        for (int c = 0; c < 6; ++c) p[c] = fmaf(tv, Wp2[kk * 6 + c], p[c]);
    }
    #pragma unroll
    for (int c = 0; c < 6; ++c) red[c][t] = p[c];
    __syncthreads();
    if (t < 6) {
        float a = 0.f;
        for (int j = 0; j < 64; ++j) a += red[t][j];
        out[(size_t)r * 6 + t] = a + bp2[t];
    }
}

__global__ __launch_bounds__(256) void sig_head_kernel(
    const float* __restrict__ zs, const float* __restrict__ zk,
    const float* __restrict__ Ws1, const float* __restrict__ bs1,
    const float* __restrict__ Ws2, const float* __restrict__ bs2,
    float* __restrict__ out)
{
    const int b = blockIdx.x, t = threadIdx.x;
    __shared__ float zrow[256];
    __shared__ float h1[256];
    zrow[t] = (t < 128) ? zs[b * 128 + t] : zk[b * 128 + t - 128];
    __syncthreads();
    float acc = bs1[t];
    for (int kk = 0; kk < 256; ++kk) acc = fmaf(zrow[kk], Ws1[kk * 256 + t], acc);
    h1[t] = gelu_f(acc);
    __syncthreads();
    if (t < 5) {
        float a = bs2[t];
        for (int kk = 0; kk < 256; ++kk) a = fmaf(h1[kk], Ws2[kk * 5 + t], a);
        out[b * 5 + t] = a;
    }
}

extern "C" void kernel_launch(void* const* d_in, const int* in_sizes, int n_in,
                              void* d_out, int out_size, void* d_ws, size_t ws_size,
                              hipStream_t stream) {
    const float* z_style   = (const float*)d_in[0];
    const float* z_skill   = (const float*)d_in[1];
    const float* W_lat     = (const float*)d_in[2];
    const float* b_lat     = (const float*)d_in[3];
    const float* temp_bias = (const float*)d_in[4];
    const float* Wq  = (const float*)d_in[5];
    const float* bq  = (const float*)d_in[6];
    const float* Wk  = (const float*)d_in[7];
    const float* bk  = (const float*)d_in[8];
    const float* Wv  = (const float*)d_in[9];
    const float* bv  = (const float*)d_in[10];
    const float* Wo  = (const float*)d_in[11];
    const float* bo  = (const float*)d_in[12];
    const float* g1  = (const float*)d_in[13];
    const float* be1 = (const float*)d_in[14];
    const float* g2  = (const float*)d_in[15];
    const float* be2 = (const float*)d_in[16];
    const float* W1  = (const float*)d_in[17];
    const float* bf1 = (const float*)d_in[18];
    const float* W2  = (const float*)d_in[19];
    const float* bf2 = (const float*)d_in[20];
    const float* Wp1 = (const float*)d_in[21];
    const float* bp1 = (const float*)d_in[22];
    const float* Wp2 = (const float*)d_in[23];
    const float* bp2 = (const float*)d_in[24];
    const float* Ws1 = (const float*)d_in[25];
    const float* bs1 = (const float*)d_in[26];
    const float* Ws2 = (const float*)d_in[27];
    const float* bs2 = (const float*)d_in[28];
    float* out = (float*)d_out;

    // ---- workspace layout (bytes), total ~222.1 MB ----
    char* Wb = (char*)d_ws;
    float* x     = (float*)(Wb + 0);             // [25600,512] fp32 residual
    u16*  xb     = (u16*)(Wb + 52428800);        // [25600,512] bf16 (LN out)
    u16*  qkv    = (u16*)(Wb + 78643200);        // [25600,1536] bf16
    u16*  cx     = (u16*)(Wb + 157286400);       // ctx bf16 [25600,512]
    u16*  ff1b   = (u16*)(Wb + 78643200);        // [25600,2048] overlays qkv+cx
    u16*  wlatT  = (u16*)(Wb + 78643200);        // [102400,256] pre-loop only
    float* t1    = (float*)(Wb + 157286400);     // head scratch (cx dead)
    u16*  qkvoT  = (u16*)(Wb + 183500800);       // 24 x [512,512]
    u16*  w1T    = (u16*)(Wb + 196083712);       // 6 x [2048,512]
    u16*  w2T    = (u16*)(Wb + 208666624);       // 6 x [512,2048]
    u16*  wp1T   = (u16*)(Wb + 221249536);       // [256,512]
    float* bqkv  = (float*)(Wb + 221511680);     // [6,1536]
    u16*  zbb    = (u16*)(Wb + 221548544);       // [128,256]
    float* pe    = (float*)(Wb + 221614080);     // [102400] fp32 PE table

    // ---- weight conversion (every launch; inputs restored each call) ----
    tconv4_kernel<<<dim3(8, 8, 24), 256, 0, stream>>>(Wq, Wk, Wv, Wo, qkvoT);
    tconv_kernel<<<dim3(32, 8, 6), 256, 0, stream>>>(W1, w1T, DMODEL, DFF,
                                                     (size_t)DMODEL * DFF, (size_t)DMODEL * DFF);
    tconv_kernel<<<dim3(8, 32, 6), 256, 0, stream>>>(W2, w2T, DFF, DMODEL,
                                                     (size_t)DMODEL * DFF, (size_t)DMODEL * DFF);
    tconv_kernel<<<dim3(1600, 4, 1), 256, 0, stream>>>(W_lat, wlatT, LATDIM, DMODEL * SEQ, 0, 0);
    tconv_kernel<<<dim3(4, 8, 1), 256, 0, stream>>>(Wp1, wp1T, DMODEL, 256, 0, 0);
    bqkv_kernel<<<NLAYER, 256, 0, stream>>>(bq, bk, bv, bqkv);
    concat_z_kernel<<<BATCH, 256, 0, stream>>>(z_style, z_skill, zbb);
    pe_kernel<<<400, 256, 0, stream>>>(pe);

    // x = gelu(z @ W_lat + b_lat) + pe  (dual fp32/bf16)
    mm_kernel<<<dim3(800), 256, 0, stream>>>(
        zbb, wlatT, b_lat, x, xb, pe, BATCH, DMODEL * SEQ, LATDIM, MM_LAT, 800);

    for (int l = 0; l < NLAYER; ++l) {
        mm256_kernel<<<dim3(12 * 100), 512, 0, stream>>>(
            xb, qkvoT + (size_t)l * 4 * 262144, bqkv + l * 1536, qkv,
            QKVS, DMODEL, MM_QKV, 12);
        attn_kernel<<<dim3(4, NHEAD, BATCH), 256, 0, stream>>>(qkv, temp_bias, cx);
        mm_kernel<<<dim3(4 * 200), 256, 0, stream>>>(
            cx, qkvoT + (size_t)(l * 4 + 3) * 262144, bo + l * DMODEL, x, nullptr, pe,
            ROWS, DMODEL, DMODEL, MM_RESID, 4);
        ln_kernel<<<ROWS / 4, 256, 0, stream>>>(x, g1 + l * DMODEL, be1 + l * DMODEL, xb);
        mm256_kernel<<<dim3(16 * 100), 512, 0, stream>>>(
            xb, w1T + (size_t)l * DMODEL * DFF, bf1 + l * DFF, ff1b,
            DFF, DMODEL, MM_GELU_BF16, 16);
        mm_kernel<<<dim3(4 * 200), 256, 0, stream>>>(
            ff1b, w2T + (size_t)l * DMODEL * DFF, bf2 + l * DMODEL, x, nullptr, pe,
            ROWS, DMODEL, DFF, MM_RESID, 4);
        ln_kernel<<<ROWS / 4, 256, 0, stream>>>(x, g2 + l * DMODEL, be2 + l * DMODEL, xb);
    }

    // heads
    mm_kernel<<<dim3(2 * 200), 256, 0, stream>>>(
        xb, wp1T, bp1, t1, nullptr, pe, ROWS, 256, DMODEL, MM_GELU_F32, 2);
    traj_head_kernel<<<ROWS, 64, 0, stream>>>(t1, Wp2, bp2, out);
    sig_head_kernel<<<BATCH, 256, 0, stream>>>(z_style, z_skill, Ws1, bs1, Ws2, bs2,
                                               out + (size_t)ROWS * OUTDIM);
}

// Round 6
// 2940.741 us; speedup vs baseline: 1.0891x; 1.0586x over previous
//
#include <hip/hip_runtime.h>
#include <math.h>

#define BATCH 128
#define DMODEL 512
#define NHEAD 8
#define NLAYER 6
#define SEQ 200
#define LATDIM 256
#define OUTDIM 6
#define DFF 2048
#define ROWS (BATCH * SEQ)   // 25600
#define QKVS 1536            // fused qkv row stride
#define VTS 264              // Vt row stride (u16): 528B, bank-rotating

typedef unsigned short u16;
typedef __attribute__((ext_vector_type(8))) short bfrag8;
typedef __attribute__((ext_vector_type(4))) float facc4;

// branch-free erf (Abramowitz-Stegun 7.1.26, |err| <= 1.5e-7) -> cheap exact-gelu
__device__ __forceinline__ float gelu_f(float v) {
    const float x = v * 0.70710678118654752f;
    const float ax = fabsf(x);
    const float t = __builtin_amdgcn_rcpf(fmaf(0.3275911f, ax, 1.0f));
    float p = fmaf(1.061405429f, t, -1.453152027f);
    p = fmaf(p, t, 1.421413741f);
    p = fmaf(p, t, -0.284496736f);
    p = fmaf(p, t, 0.254829592f);
    p = p * t;
    const float e = __expf(-ax * ax);
    float er = fmaf(-p, e, 1.0f);          // erf(|x|)
    er = copysignf(er, x);
    return 0.5f * v * (1.0f + er);
}
__device__ __forceinline__ u16 f2bf(float f) {
    unsigned u = __float_as_uint(f);
    u += 0x7fffu + ((u >> 16) & 1u);
    return (u16)(u >> 16);
}
// async global->LDS, 16B per lane; HW dest = wave-uniform base + lane*16
__device__ __forceinline__ void gl_lds16(const u16* g, u16* l) {
    __builtin_amdgcn_global_load_lds(
        (const __attribute__((address_space(1))) void*)(uintptr_t)g,
        (__attribute__((address_space(3))) void*)(uintptr_t)l,
        16, 0, 0);
}

enum { MM_QKV = 0, MM_RESID = 1, MM_GELU_BF16 = 2, MM_GELU_F32 = 3, MM_LAT = 4 };

// ---------------------------------------------------------------------------
// bf16 MFMA GEMM (r3 structure): 3-stage global_load_lds pipeline, counted
// vmcnt (steady vmcnt(8): 12 loads / 3 tiles in flight), two barriers/iter,
// XCD-chunked swizzle, setprio on MFMA cluster.
// 128x128 tile, BK=32, 4 waves x 64x64 subtile of 16x16x32 MFMA.
// Used only for the latent GEMM (M=128) and the Wp1 head (N=256).
// ---------------------------------------------------------------------------
__global__ __launch_bounds__(256) void mm_kernel(
    const u16* __restrict__ A, const u16* __restrict__ Bt,
    const float* __restrict__ bias, float* __restrict__ Cf, u16* __restrict__ Cb,
    const float* __restrict__ pe, int M, int N, int K, int mode, int gx)
{
    __shared__ __align__(16) u16 As[3 * 4096];
    __shared__ __align__(16) u16 Bs[3 * 4096];
    const int tid = threadIdx.x;

    const unsigned nwg = gridDim.x, cpx = nwg >> 3;
    const unsigned id = blockIdx.x;
    const unsigned swz = (id & 7u) * cpx + (id >> 3);
    const int bx = (int)(swz % (unsigned)gx);
    const int by = (int)(swz / (unsigned)gx);
    const int row0 = by * 128, col0 = bx * 128;

    const int lane = tid & 63, w = tid >> 6;
    const int m_w = (w & 1) << 6, n_w = (w >> 1) << 6;
    const int l16 = lane & 15, quad = lane >> 4;

    const int r0 = tid >> 2;
    const int seg = ((tid & 3) ^ ((tid >> 3) & 3)) << 3;   // permuted k-chunk, elems
    const u16* Ag0 = A + (size_t)(row0 + r0) * K + seg;
    const u16* Ag1 = A + (size_t)(row0 + r0 + 64) * K + seg;
    const u16* Bg0 = Bt + (size_t)(col0 + r0) * K + seg;
    const u16* Bg1 = Bt + (size_t)(col0 + r0 + 64) * K + seg;

    const int pos = (quad ^ ((l16 >> 1) & 3)) << 3;        // frag read chunk, elems

    facc4 acc[4][4] = {};
    const int iters = K >> 5;          // >= 8 for all call sites

    u16* Ald = As + w * 512;
    u16* Bld = Bs + w * 512;
    #pragma unroll
    for (int pf = 0; pf < 3; ++pf) {
        const int ko = pf << 5;
        const int bo = pf << 12;
        gl_lds16(Ag0 + ko, Ald + bo);
        gl_lds16(Ag1 + ko, Ald + bo + 2048);
        gl_lds16(Bg0 + ko, Bld + bo);
        gl_lds16(Bg1 + ko, Bld + bo + 2048);
    }

    int b = 0;
    for (int it = 0; it < iters; ++it) {
        const int ahead = iters - 1 - it;
        if (ahead >= 2)      asm volatile("s_waitcnt vmcnt(8)" ::: "memory");
        else if (ahead == 1) asm volatile("s_waitcnt vmcnt(4)" ::: "memory");
        else                 asm volatile("s_waitcnt vmcnt(0)" ::: "memory");
        __builtin_amdgcn_s_barrier();           // all waves' tile-it loads done
        asm volatile("" ::: "memory");          // pin ds_reads below barrier

        const u16* Ab = As + (b << 12);
        const u16* Bb = Bs + (b << 12);
        bfrag8 af[4], bf[4];
        #pragma unroll
        for (int i = 0; i < 4; ++i)
            af[i] = *(const bfrag8*)&Ab[(m_w + i * 16 + l16) * 32 + pos];
        #pragma unroll
        for (int j = 0; j < 4; ++j)
            bf[j] = *(const bfrag8*)&Bb[(n_w + j * 16 + l16) * 32 + pos];
        __builtin_amdgcn_s_setprio(1);
        #pragma unroll
        for (int i = 0; i < 4; ++i)
            #pragma unroll
            for (int j = 0; j < 4; ++j)
                acc[i][j] = __builtin_amdgcn_mfma_f32_16x16x32_bf16(
                    af[i], bf[j], acc[i][j], 0, 0, 0);
        __builtin_amdgcn_s_setprio(0);

        // fence: MFMAs (and thus their lgkm drains) complete before barrier,
        // so no wave can overwrite buf b while another still reads it (rule 18)
        __builtin_amdgcn_sched_barrier(0);
        asm volatile("" ::: "memory");
        __builtin_amdgcn_s_barrier();
        asm volatile("" ::: "memory");

        if (it + 3 < iters) {                   // refill just-consumed buffer
            const int ko = (it + 3) << 5;
            const int bo = b << 12;
            gl_lds16(Ag0 + ko, Ald + bo);
            gl_lds16(Ag1 + ko, Ald + bo + 2048);
            gl_lds16(Bg0 + ko, Bld + bo);
            gl_lds16(Bg1 + ko, Bld + bo + 2048);
        }
        b = (b == 2) ? 0 : b + 1;
    }

    #pragma unroll
    for (int i = 0; i < 4; ++i) {
        #pragma unroll
        for (int r = 0; r < 4; ++r) {
            const int row = row0 + m_w + i * 16 + quad * 4 + r;
            #pragma unroll
            for (int j = 0; j < 4; ++j) {
                const int col = col0 + n_w + j * 16 + l16;
                float v = acc[i][j][r] + bias[col];
                const size_t idx = (size_t)row * N + col;
                if (mode == MM_QKV) {
                    Cb[idx] = f2bf(v);
                } else if (mode == MM_RESID) {
                    Cf[idx] += v;
                } else if (mode == MM_GELU_BF16) {
                    Cb[idx] = f2bf(gelu_f(v));
                } else if (mode == MM_GELU_F32) {
                    Cf[idx] = gelu_f(v);
                } else { // MM_LAT: gelu + precomputed positional encoding, dual out
                    v = gelu_f(v) + pe[col];
                    Cf[idx] = v;
                    Cb[idx] = f2bf(v);
                }
            }
        }
    }
}

// ---------------------------------------------------------------------------
// 256x128-tile variant, 8 waves (512 threads), wave grid 4Mx2N, same proven
// 64x64 wave subtile / chunk permutation / depth-3 counted-vmcnt pipeline.
// Now serves ALL loop GEMMs (QKV, FF1, O-proj, FF2):
//  - QKV/FF1: halves block generations vs 128^2.
//  - O-proj/FF2 (N=512): grid 400 blocks @ 2 blocks/CU (72KB LDS) -> 50
//    blocks/XCD vs 64 resident slots: ONE generation, NO straggler tail.
//    (r5 evidence: 800-block 128^2 grid = 100 blocks/XCD vs 96 slots ->
//    4 stragglers ~double the makespan; Occ 23.5% = avg of 37.5% + tail,
//    and 117us ~= 1.6 x 73us steady-state model.)
//  - staged bytes per MFMA: 187 B vs 256 B at 128^2.
// ---------------------------------------------------------------------------
__global__ __launch_bounds__(512) void mm256_kernel(
    const u16* __restrict__ A, const u16* __restrict__ Bt,
    const float* __restrict__ bias, float* __restrict__ Cf, u16* __restrict__ Cb,
    int N, int K, int mode, int gx)
{
    __shared__ __align__(16) u16 As[3 * 8192];   // 256 rows x 32 elems / buf
    __shared__ __align__(16) u16 Bs[3 * 4096];   // 128 rows x 32 elems / buf
    const int tid = threadIdx.x;

    const unsigned nwg = gridDim.x, cpx = nwg >> 3;
    const unsigned id = blockIdx.x;
    const unsigned swz = (id & 7u) * cpx + (id >> 3);
    const int bx = (int)(swz % (unsigned)gx);
    const int by = (int)(swz / (unsigned)gx);
    const int row0 = by * 256, col0 = bx * 128;

    const int lane = tid & 63, w = tid >> 6;
    const int m_w = (w & 3) << 6, n_w = (w >> 2) << 6;
    const int l16 = lane & 15, quad = lane >> 4;

    const int r0 = tid >> 2;                               // 0..127
    const int seg = ((tid & 3) ^ ((tid >> 3) & 3)) << 3;
    const u16* Ag0 = A + (size_t)(row0 + r0) * K + seg;
    const u16* Ag1 = A + (size_t)(row0 + r0 + 128) * K + seg;
    const u16* Bg0 = Bt + (size_t)(col0 + r0) * K + seg;

    const int pos = (quad ^ ((l16 >> 1) & 3)) << 3;

    facc4 acc[4][4] = {};
    const int iters = K >> 5;          // 16 (K=512) or 64 (K=2048)

    u16* Ald = As + w * 512;           // wave-slice DMA bases (64 chunks/wave)
    u16* Bld = Bs + w * 512;
    #pragma unroll
    for (int pf = 0; pf < 3; ++pf) {
        const int ko = pf << 5;
        gl_lds16(Ag0 + ko, Ald + pf * 8192);
        gl_lds16(Ag1 + ko, Ald + pf * 8192 + 4096);
        gl_lds16(Bg0 + ko, Bld + pf * 4096);
    }

    int b = 0;
    for (int it = 0; it < iters; ++it) {
        const int ahead = iters - 1 - it;   // 3 loads per tile per thread
        if (ahead >= 2)      asm volatile("s_waitcnt vmcnt(6)" ::: "memory");
        else if (ahead == 1) asm volatile("s_waitcnt vmcnt(3)" ::: "memory");
        else                 asm volatile("s_waitcnt vmcnt(0)" ::: "memory");
        __builtin_amdgcn_s_barrier();
        asm volatile("" ::: "memory");

        const u16* Ab = As + b * 8192;
        const u16* Bb = Bs + b * 4096;
        bfrag8 af[4], bf[4];
        #pragma unroll
        for (int i = 0; i < 4; ++i)
            af[i] = *(const bfrag8*)&Ab[(m_w + i * 16 + l16) * 32 + pos];
        #pragma unroll
        for (int j = 0; j < 4; ++j)
            bf[j] = *(const bfrag8*)&Bb[(n_w + j * 16 + l16) * 32 + pos];
        __builtin_amdgcn_s_setprio(1);
        #pragma unroll
        for (int i = 0; i < 4; ++i)
            #pragma unroll
            for (int j = 0; j < 4; ++j)
                acc[i][j] = __builtin_amdgcn_mfma_f32_16x16x32_bf16(
                    af[i], bf[j], acc[i][j], 0, 0, 0);
        __builtin_amdgcn_s_setprio(0);

        __builtin_amdgcn_sched_barrier(0);
        asm volatile("" ::: "memory");
        __builtin_amdgcn_s_barrier();
        asm volatile("" ::: "memory");

        if (it + 3 < iters) {
            const int ko = (it + 3) << 5;
            gl_lds16(Ag0 + ko, Ald + b * 8192);
            gl_lds16(Ag1 + ko, Ald + b * 8192 + 4096);
            gl_lds16(Bg0 + ko, Bld + b * 4096);
        }
        b = (b == 2) ? 0 : b + 1;
    }

    #pragma unroll
    for (int i = 0; i < 4; ++i) {
        #pragma unroll
        for (int r = 0; r < 4; ++r) {
            const int row = row0 + m_w + i * 16 + quad * 4 + r;
            #pragma unroll
            for (int j = 0; j < 4; ++j) {
                const int col = col0 + n_w + j * 16 + l16;
                float v = acc[i][j][r] + bias[col];
                const size_t idx = (size_t)row * N + col;
                if (mode == MM_QKV)        Cb[idx] = f2bf(v);
                else if (mode == MM_RESID) Cf[idx] += v;
                else                       Cb[idx] = f2bf(gelu_f(v));  // GELU_BF16
            }
        }
    }
}

// positional encoding table pe[s*512+d], 102400 entries
__global__ __launch_bounds__(256) void pe_kernel(float* __restrict__ pe)
{
    const int idx = blockIdx.x * 256 + threadIdx.x;
    const int s = idx >> 9, d = idx & 511;
    const float ang = (float)s * expf((float)(d & ~1) * (-9.2103403719761836f / 512.0f));
    pe[idx] = (d & 1) ? cosf(ang) : sinf(ang);
}

// ---------------------------------------------------------------------------
// MFMA attention. Grid (qtile=4, h=8, b=128); 4 waves; wave = 16 queries.
// ---------------------------------------------------------------------------
__global__ __launch_bounds__(256) void attn_kernel(
    const u16* __restrict__ qkv, const float* __restrict__ tb,
    u16* __restrict__ ctxb)
{
    const int qt = blockIdx.x, h = blockIdx.y, b = blockIdx.z;
    const int tid = threadIdx.x;
    const int w = tid >> 6, lane = tid & 63;
    const int l16 = lane & 15, quad = lane >> 4;

    __shared__ __align__(16) u16 kv[16896];        // Ks[208][64] / Vt[64][264]
    __shared__ __align__(16) u16 Ps[4][16][232];   // softmaxed P per wave

    const size_t rowbase = (size_t)b * SEQ;
    const int q0w = qt * 64 + w * 16;

    for (int g = w; g < 26; g += 4) {
        const int c = g * 64 + lane;
        const int key = c >> 3, seg = c & 7;
        const int krow = key < 200 ? key : 199;
        gl_lds16(qkv + (rowbase + krow) * QKVS + 512 + h * 64 +
                 ((seg ^ (key & 7)) << 3),
                 kv + g * 512);
    }
    int qrow = (int)rowbase + q0w + l16;
    if (qrow > ROWS - 1) qrow = ROWS - 1;
    const u16* qp = qkv + (size_t)qrow * QKVS + h * 64 + quad * 8;
    bfrag8 aq0 = *(const bfrag8*)(qp);
    bfrag8 aq1 = *(const bfrag8*)(qp + 32);
    __syncthreads();

    facc4 sc[13];
    #pragma unroll
    for (int nt = 0; nt < 13; ++nt) {
        const int key = nt * 16 + l16, kk = key & 7;
        bfrag8 b0 = *(const bfrag8*)&kv[key * 64 + ((quad ^ kk) << 3)];
        bfrag8 b1 = *(const bfrag8*)&kv[key * 64 + (((4 + quad) ^ kk) << 3)];
        facc4 a = {};
        a = __builtin_amdgcn_mfma_f32_16x16x32_bf16(aq0, b0, a, 0, 0, 0);
        a = __builtin_amdgcn_mfma_f32_16x16x32_bf16(aq1, b1, a, 0, 0, 0);
        sc[nt] = a;
    }
    __syncthreads();

    for (int c = 0; c < 7; ++c) {
        const int key = c * 32 + (tid & 31);
        const int dkb = (tid >> 5) * 8;
        u16 vals[8];
        if (key < 200) {
            *(uint4*)vals = *(const uint4*)(qkv + (rowbase + key) * QKVS +
                                            1024 + h * 64 + dkb);
        } else {
            #pragma unroll
            for (int i = 0; i < 8; ++i) vals[i] = 0;
        }
        #pragma unroll
        for (int i = 0; i < 8; ++i)
            kv[(dkb + i) * VTS + key] = vals[i];
    }

    #pragma unroll
    for (int r = 0; r < 4; ++r) {
        const int i = q0w + quad * 4 + r;
        #pragma unroll
        for (int nt = 0; nt < 13; ++nt) {
            const int j = nt * 16 + l16;
            float s;
            if (j < 200) {
                const float tbv = (i < 200) ? tb[(h * 200 + i) * 200 + j] : 0.f;
                s = sc[nt][r] * 0.125f + tbv;
            } else s = -INFINITY;
            sc[nt][r] = s;
        }
        float m = sc[0][r];
        #pragma unroll
        for (int nt = 1; nt < 13; ++nt) m = fmaxf(m, sc[nt][r]);
        #pragma unroll
        for (int off = 8; off > 0; off >>= 1) m = fmaxf(m, __shfl_xor(m, off, 64));
        float ssum = 0.f;
        #pragma unroll
        for (int nt = 0; nt < 13; ++nt) {
            const float e = __expf(sc[nt][r] - m);
            sc[nt][r] = e; ssum += e;
        }
        #pragma unroll
        for (int off = 8; off > 0; off >>= 1) ssum += __shfl_xor(ssum, off, 64);
        const float inv = 1.0f / ssum;
        #pragma unroll
        for (int nt = 0; nt < 13; ++nt)
            Ps[w][quad * 4 + r][nt * 16 + l16] = f2bf(sc[nt][r] * inv);
        Ps[w][quad * 4 + r][208 + l16] = 0;
    }
    __syncthreads();

    facc4 pacc[4] = {};
    for (int ks = 0; ks < 7; ++ks) {
        bfrag8 ap = *(const bfrag8*)&Ps[w][l16][ks * 32 + quad * 8];
        #pragma unroll
        for (int nt = 0; nt < 4; ++nt) {
            const int dkrow = nt * 16 + l16;
            bfrag8 bv = *(const bfrag8*)&kv[dkrow * VTS + ks * 32 + quad * 8];
            pacc[nt] = __builtin_amdgcn_mfma_f32_16x16x32_bf16(ap, bv, pacc[nt], 0, 0, 0);
        }
    }

    #pragma unroll
    for (int r = 0; r < 4; ++r) {
        const int i = q0w + quad * 4 + r;
        if (i < 200) {
            #pragma unroll
            for (int nt = 0; nt < 4; ++nt)
                ctxb[(rowbase + i) * 512 + h * 64 + nt * 16 + l16] = f2bf(pacc[nt][r]);
        }
    }
}

// ---------------------------------------------------------------------------
// Transpose-convert W [K,N] fp32 -> Wt [N,K] bf16, batched over blockIdx.z
// ---------------------------------------------------------------------------
__global__ __launch_bounds__(256) void tconv_kernel(
    const float* __restrict__ W, u16* __restrict__ O, int K, int N,
    size_t wStride, size_t oStride)
{
    __shared__ u16 T[64][80];
    const float* Wz = W + wStride * blockIdx.z;
    u16* Oz = O + oStride * blockIdx.z;
    const int n0 = blockIdx.x * 64, k0 = blockIdx.y * 64, t = threadIdx.x;
    {
        const int kr = t >> 2, seg = t & 3;
        const float* wp = Wz + (size_t)(k0 + kr) * N + n0 + seg * 16;
        alignas(16) u16 tmp[16];
        #pragma unroll
        for (int q = 0; q < 4; ++q) {
            float4 f = ((const float4*)wp)[q];
            tmp[q * 4 + 0] = f2bf(f.x); tmp[q * 4 + 1] = f2bf(f.y);
            tmp[q * 4 + 2] = f2bf(f.z); tmp[q * 4 + 3] = f2bf(f.w);
        }
        *(uint4*)&T[kr][seg * 16]     = *(uint4*)&tmp[0];
        *(uint4*)&T[kr][seg * 16 + 8] = *(uint4*)&tmp[8];
    }
    __syncthreads();
    {
        const int n = t >> 2, kseg = t & 3;
        alignas(16) u16 o[16];
        #pragma unroll
        for (int i = 0; i < 16; ++i) o[i] = T[kseg * 16 + i][n];
        uint4* op = (uint4*)(Oz + (size_t)(n0 + n) * K + k0 + kseg * 16);
        op[0] = *(uint4*)&o[0];
        op[1] = *(uint4*)&o[8];
    }
}

// qkvo batch: z = layer*4 + {q,k,v,o}, all 512x512
__global__ __launch_bounds__(256) void tconv4_kernel(
    const float* __restrict__ Wq, const float* __restrict__ Wk,
    const float* __restrict__ Wv, const float* __restrict__ Wo,
    u16* __restrict__ Out)
{
    __shared__ u16 T[64][80];
    const int z = blockIdx.z, layer = z >> 2, m = z & 3;
    const float* W = (m == 0 ? Wq : m == 1 ? Wk : m == 2 ? Wv : Wo)
                     + (size_t)layer * 262144;
    u16* O = Out + (size_t)z * 262144;
    const int n0 = blockIdx.x * 64, k0 = blockIdx.y * 64, t = threadIdx.x;
    {
        const int kr = t >> 2, seg = t & 3;
        const float* wp = W + (size_t)(k0 + kr) * 512 + n0 + seg * 16;
        alignas(16) u16 tmp[16];
        #pragma unroll
        for (int q = 0; q < 4; ++q) {
            float4 f = ((const float4*)wp)[q];
            tmp[q * 4 + 0] = f2bf(f.x); tmp[q * 4 + 1] = f2bf(f.y);
            tmp[q * 4 + 2] = f2bf(f.z); tmp[q * 4 + 3] = f2bf(f.w);
        }
        *(uint4*)&T[kr][seg * 16]     = *(uint4*)&tmp[0];
        *(uint4*)&T[kr][seg * 16 + 8] = *(uint4*)&tmp[8];
    }
    __syncthreads();
    {
        const int n = t >> 2, kseg = t & 3;
        alignas(16) u16 o[16];
        #pragma unroll
        for (int i = 0; i < 16; ++i) o[i] = T[kseg * 16 + i][n];
        uint4* op = (uint4*)(O + (size_t)(n0 + n) * 512 + k0 + kseg * 16);
        op[0] = *(uint4*)&o[0];
        op[1] = *(uint4*)&o[8];
    }
}

// concat biases: bqkv[l][1536] = [bq[l] | bk[l] | bv[l]]
__global__ __launch_bounds__(256) void bqkv_kernel(
    const float* __restrict__ bq, const float* __restrict__ bk,
    const float* __restrict__ bv, float* __restrict__ o)
{
    const int l = blockIdx.x, t = threadIdx.x;
    for (int c = t; c < 1536; c += 256) {
        float v = (c < 512) ? bq[l * 512 + c]
                : (c < 1024) ? bk[l * 512 + c - 512]
                             : bv[l * 512 + c - 1024];
        o[l * 1536 + c] = v;
    }
}

// LayerNorm: 1 wave per row, 4 rows/block, vectorized, shuffle-only reduce
__global__ __launch_bounds__(256) void ln_kernel(
    float* __restrict__ x, const float* __restrict__ g,
    const float* __restrict__ bb, u16* __restrict__ xb)
{
    const int w = threadIdx.x >> 6, lane = threadIdx.x & 63;
    const size_t row = (size_t)blockIdx.x * 4 + w;
    float* xr = x + row * DMODEL;
    u16* xbr = xb + row * DMODEL;
    const int c = lane * 8;
    float4 a = *(const float4*)(xr + c);
    float4 b = *(const float4*)(xr + c + 4);
    float s = a.x + a.y + a.z + a.w + b.x + b.y + b.z + b.w;
    #pragma unroll
    for (int off = 32; off > 0; off >>= 1) s += __shfl_xor(s, off, 64);
    const float mu = s * (1.0f / 512.0f);
    a.x -= mu; a.y -= mu; a.z -= mu; a.w -= mu;
    b.x -= mu; b.y -= mu; b.z -= mu; b.w -= mu;
    float v = a.x * a.x + a.y * a.y + a.z * a.z + a.w * a.w
            + b.x * b.x + b.y * b.y + b.z * b.z + b.w * b.w;
    #pragma unroll
    for (int off = 32; off > 0; off >>= 1) v += __shfl_xor(v, off, 64);
    const float rstd = rsqrtf(v * (1.0f / 512.0f) + 1e-5f);
    float4 g0 = *(const float4*)(g + c), g1 = *(const float4*)(g + c + 4);
    float4 b0 = *(const float4*)(bb + c), b1 = *(const float4*)(bb + c + 4);
    float4 o0, o1;
    o0.x = a.x * rstd * g0.x + b0.x; o0.y = a.y * rstd * g0.y + b0.y;
    o0.z = a.z * rstd * g0.z + b0.z; o0.w = a.w * rstd * g0.w + b0.w;
    o1.x = b.x * rstd * g1.x + b1.x; o1.y = b.y * rstd * g1.y + b1.y;
    o1.z = b.z * rstd * g1.z + b1.z; o1.w = b.w * rstd * g1.w + b1.w;
    *(float4*)(xr + c) = o0;
    *(float4*)(xr + c + 4) = o1;
    alignas(16) u16 ob[8] = { f2bf(o0.x), f2bf(o0.y), f2bf(o0.z), f2bf(o0.w),
                              f2bf(o1.x), f2bf(o1.y), f2bf(o1.z), f2bf(o1.w) };
    *(uint4*)(xbr + c) = *(uint4*)ob;
}

__global__ __launch_bounds__(256) void concat_z_kernel(
    const float* __restrict__ zs, const float* __restrict__ zk, u16* __restrict__ z)
{
    const int b = blockIdx.x, t = threadIdx.x;
    z[b * 256 + t] = f2bf((t < 128) ? zs[b * 128 + t] : zk[b * 128 + t - 128]);
}

__global__ __launch_bounds__(64) void traj_head_kernel(
    const float* __restrict__ t1, const float* __restrict__ Wp2,
    const float* __restrict__ bp2, float* __restrict__ out)
{
    const int r = blockIdx.x, t = threadIdx.x;
    __shared__ float red[6][64];
    float p[6] = {};
    const float* tr = t1 + (size_t)r * 256;
    for (int kk = t; kk < 256; kk += 64) {
        float tv = tr[kk];
        #pragma unroll
        for (int c = 0; c < 6; ++c) p[c] = fmaf(tv, Wp2[kk * 6 + c], p[c]);
    }
    #pragma unroll
    for (int c = 0; c < 6; ++c) red[c][t] = p[c];
    __syncthreads();
    if (t < 6) {
        float a = 0.f;
        for (int j = 0; j < 64; ++j) a += red[t][j];
        out[(size_t)r * 6 + t] = a + bp2[t];
    }
}

__global__ __launch_bounds__(256) void sig_head_kernel(
    const float* __restrict__ zs, const float* __restrict__ zk,
    const float* __restrict__ Ws1, const float* __restrict__ bs1,
    const float* __restrict__ Ws2, const float* __restrict__ bs2,
    float* __restrict__ out)
{
    const int b = blockIdx.x, t = threadIdx.x;
    __shared__ float zrow[256];
    __shared__ float h1[256];
    zrow[t] = (t < 128) ? zs[b * 128 + t] : zk[b * 128 + t - 128];
    __syncthreads();
    float acc = bs1[t];
    for (int kk = 0; kk < 256; ++kk) acc = fmaf(zrow[kk], Ws1[kk * 256 + t], acc);
    h1[t] = gelu_f(acc);
    __syncthreads();
    if (t < 5) {
        float a = bs2[t];
        for (int kk = 0; kk < 256; ++kk) a = fmaf(h1[kk], Ws2[kk * 5 + t], a);
        out[b * 5 + t] = a;
    }
}

extern "C" void kernel_launch(void* const* d_in, const int* in_sizes, int n_in,
                              void* d_out, int out_size, void* d_ws, size_t ws_size,
                              hipStream_t stream) {
    const float* z_style   = (const float*)d_in[0];
    const float* z_skill   = (const float*)d_in[1];
    const float* W_lat     = (const float*)d_in[2];
    const float* b_lat     = (const float*)d_in[3];
    const float* temp_bias = (const float*)d_in[4];
    const float* Wq  = (const float*)d_in[5];
    const float* bq  = (const float*)d_in[6];
    const float* Wk  = (const float*)d_in[7];
    const float* bk  = (const float*)d_in[8];
    const float* Wv  = (const float*)d_in[9];
    const float* bv  = (const float*)d_in[10];
    const float* Wo  = (const float*)d_in[11];
    const float* bo  = (const float*)d_in[12];
    const float* g1  = (const float*)d_in[13];
    const float* be1 = (const float*)d_in[14];
    const float* g2  = (const float*)d_in[15];
    const float* be2 = (const float*)d_in[16];
    const float* W1  = (const float*)d_in[17];
    const float* bf1 = (const float*)d_in[18];
    const float* W2  = (const float*)d_in[19];
    const float* bf2 = (const float*)d_in[20];
    const float* Wp1 = (const float*)d_in[21];
    const float* bp1 = (const float*)d_in[22];
    const float* Wp2 = (const float*)d_in[23];
    const float* bp2 = (const float*)d_in[24];
    const float* Ws1 = (const float*)d_in[25];
    const float* bs1 = (const float*)d_in[26];
    const float* Ws2 = (const float*)d_in[27];
    const float* bs2 = (const float*)d_in[28];
    float* out = (float*)d_out;

    // ---- workspace layout (bytes), total ~222.1 MB ----
    char* Wb = (char*)d_ws;
    float* x     = (float*)(Wb + 0);             // [25600,512] fp32 residual
    u16*  xb     = (u16*)(Wb + 52428800);        // [25600,512] bf16 (LN out)
    u16*  qkv    = (u16*)(Wb + 78643200);        // [25600,1536] bf16
    u16*  cx     = (u16*)(Wb + 157286400);       // ctx bf16 [25600,512]
    u16*  ff1b   = (u16*)(Wb + 78643200);        // [25600,2048] overlays qkv+cx
    u16*  wlatT  = (u16*)(Wb + 78643200);        // [102400,256] pre-loop only
    float* t1    = (float*)(Wb + 157286400);     // head scratch (cx dead)
    u16*  qkvoT  = (u16*)(Wb + 183500800);       // 24 x [512,512]
    u16*  w1T    = (u16*)(Wb + 196083712);       // 6 x [2048,512]
    u16*  w2T    = (u16*)(Wb + 208666624);       // 6 x [512,2048]
    u16*  wp1T   = (u16*)(Wb + 221249536);       // [256,512]
    float* bqkv  = (float*)(Wb + 221511680);     // [6,1536]
    u16*  zbb    = (u16*)(Wb + 221548544);       // [128,256]
    float* pe    = (float*)(Wb + 221614080);     // [102400] fp32 PE table

    // ---- weight conversion (every launch; inputs restored each call) ----
    tconv4_kernel<<<dim3(8, 8, 24), 256, 0, stream>>>(Wq, Wk, Wv, Wo, qkvoT);
    tconv_kernel<<<dim3(32, 8, 6), 256, 0, stream>>>(W1, w1T, DMODEL, DFF,
                                                     (size_t)DMODEL * DFF, (size_t)DMODEL * DFF);
    tconv_kernel<<<dim3(8, 32, 6), 256, 0, stream>>>(W2, w2T, DFF, DMODEL,
                                                     (size_t)DMODEL * DFF, (size_t)DMODEL * DFF);
    tconv_kernel<<<dim3(1600, 4, 1), 256, 0, stream>>>(W_lat, wlatT, LATDIM, DMODEL * SEQ, 0, 0);
    tconv_kernel<<<dim3(4, 8, 1), 256, 0, stream>>>(Wp1, wp1T, DMODEL, 256, 0, 0);
    bqkv_kernel<<<NLAYER, 256, 0, stream>>>(bq, bk, bv, bqkv);
    concat_z_kernel<<<BATCH, 256, 0, stream>>>(z_style, z_skill, zbb);
    pe_kernel<<<400, 256, 0, stream>>>(pe);

    // x = gelu(z @ W_lat + b_lat) + pe  (dual fp32/bf16)
    mm_kernel<<<dim3(800), 256, 0, stream>>>(
        zbb, wlatT, b_lat, x, xb, pe, BATCH, DMODEL * SEQ, LATDIM, MM_LAT, 800);

    for (int l = 0; l < NLAYER; ++l) {
        mm256_kernel<<<dim3(12 * 100), 512, 0, stream>>>(
            xb, qkvoT + (size_t)l * 4 * 262144, bqkv + l * 1536, nullptr, qkv,
            QKVS, DMODEL, MM_QKV, 12);
        attn_kernel<<<dim3(4, NHEAD, BATCH), 256, 0, stream>>>(qkv, temp_bias, cx);
        mm256_kernel<<<dim3(4 * 100), 512, 0, stream>>>(
            cx, qkvoT + (size_t)(l * 4 + 3) * 262144, bo + l * DMODEL, x, nullptr,
            DMODEL, DMODEL, MM_RESID, 4);
        ln_kernel<<<ROWS / 4, 256, 0, stream>>>(x, g1 + l * DMODEL, be1 + l * DMODEL, xb);
        mm256_kernel<<<dim3(16 * 100), 512, 0, stream>>>(
            xb, w1T + (size_t)l * DMODEL * DFF, bf1 + l * DFF, nullptr, ff1b,
            DFF, DMODEL, MM_GELU_BF16, 16);
        mm256_kernel<<<dim3(4 * 100), 512, 0, stream>>>(
            ff1b, w2T + (size_t)l * DMODEL * DFF, bf2 + l * DMODEL, x, nullptr,
            DMODEL, DFF, MM_RESID, 4);
        ln_kernel<<<ROWS / 4, 256, 0, stream>>>(x, g2 + l * DMODEL, be2 + l * DMODEL, xb);
    }

    // heads
    mm_kernel<<<dim3(2 * 200), 256, 0, stream>>>(
        xb, wp1T, bp1, t1, nullptr, pe, ROWS, 256, DMODEL, MM_GELU_F32, 2);
    traj_head_kernel<<<ROWS, 64, 0, stream>>>(t1, Wp2, bp2, out);
    sig_head_kernel<<<BATCH, 256, 0, stream>>>(z_style, z_skill, Ws1, bs1, Ws2, bs2,
                                               out + (size_t)ROWS * OUTDIM);
}

// Round 8
// 2579.535 us; speedup vs baseline: 1.2416x; 1.1400x over previous
//
#include <hip/hip_runtime.h>
#include <math.h>

#define BATCH 128
#define DMODEL 512
#define NHEAD 8
#define NLAYER 6
#define SEQ 200
#define LATDIM 256
#define OUTDIM 6
#define DFF 2048
#define ROWS (BATCH * SEQ)   // 25600
#define QKVS 1536            // fused qkv row stride
#define VTS 264              // Vt row stride (u16): 528B, bank-rotating

typedef unsigned short u16;
typedef __attribute__((ext_vector_type(8))) short bfrag8;
typedef __attribute__((ext_vector_type(4))) float facc4;

// HW packed f32->bf16 (RNE), S0 -> low 16, S1 -> high 16 (AMD pack convention)
__device__ __forceinline__ unsigned cvt_pk_bf16(float lo, float hi) {
    unsigned r;
    asm("v_cvt_pk_bf16_f32 %0, %1, %2" : "=v"(r) : "v"(lo), "v"(hi));
    return r;
}
// exact-gelu via A&S 7.1.26 erf (|err|<=1.5e-7); uses v*erf(x)=|v|*erf(|x|)
// so no copysign; 0.5 factors folded into halved polynomial coefficients.
__device__ __forceinline__ float gelu_f(float v) {
    const float av = fabsf(v);
    const float ax = av * 0.70710678118654752f;
    const float t = __builtin_amdgcn_rcpf(fmaf(0.3275911f, ax, 1.0f));
    float p = fmaf(0.5305027145f, t, -0.7265760135f);   // 0.5*a5, 0.5*a4
    p = fmaf(p, t, 0.7107068705f);                       // 0.5*a3
    p = fmaf(p, t, -0.142248368f);                       // 0.5*a2
    p = fmaf(p, t, 0.127414796f);                        // 0.5*a1
    p = p * t;
    const float e = __expf(-ax * ax);
    const float er05 = fmaf(-p, e, 0.5f);                // 0.5*erf(|x|)
    return fmaf(av, er05, 0.5f * v);
}
__device__ __forceinline__ u16 f2bf(float f) {
    unsigned u = __float_as_uint(f);
    u += 0x7fffu + ((u >> 16) & 1u);
    return (u16)(u >> 16);
}
// async global->LDS, 16B per lane; HW dest = wave-uniform base + lane*16
__device__ __forceinline__ void gl_lds16(const u16* g, u16* l) {
    __builtin_amdgcn_global_load_lds(
        (const __attribute__((address_space(1))) void*)(uintptr_t)g,
        (__attribute__((address_space(3))) void*)(uintptr_t)l,
        16, 0, 0);
}

enum { MM_QKV = 0, MM_RESID = 1, MM_GELU_BF16 = 2, MM_GELU_F32 = 3, MM_LAT = 4 };

// ---------------------------------------------------------------------------
// bf16 MFMA GEMM (r3 structure): NBUF-stage global_load_lds pipeline, counted
// vmcnt, two barriers/iter, XCD-chunked swizzle, setprio on MFMA cluster.
// 128x128 tile, BK=32, 4 waves x 64x64 subtile of 16x16x32 MFMA.
// NBUF=3 (48KB, 3 blk/CU) for deep-K; NBUF=2 (32KB, 5 blk/CU) for the latent
// GEMM: its 800-block grid then fits ONE residency generation per XCD
// (160 slots vs 100 blocks) -> no straggler tail (r5 mechanism), and with
// only 8 K-iters in a single generation the depth loss is minor.
// ---------------------------------------------------------------------------
template<int NBUF>
__global__ __launch_bounds__(256) void mm_kernel(
    const u16* __restrict__ A, const u16* __restrict__ Bt,
    const float* __restrict__ bias, float* __restrict__ Cf, u16* __restrict__ Cb,
    const float* __restrict__ pe, int M, int N, int K, int mode, int gx)
{
    __shared__ __align__(16) u16 As[NBUF * 4096];
    __shared__ __align__(16) u16 Bs[NBUF * 4096];
    const int tid = threadIdx.x;

    const unsigned nwg = gridDim.x, cpx = nwg >> 3;
    const unsigned id = blockIdx.x;
    const unsigned swz = (id & 7u) * cpx + (id >> 3);
    const int bx = (int)(swz % (unsigned)gx);
    const int by = (int)(swz / (unsigned)gx);
    const int row0 = by * 128, col0 = bx * 128;

    const int lane = tid & 63, w = tid >> 6;
    const int m_w = (w & 1) << 6, n_w = (w >> 1) << 6;
    const int l16 = lane & 15, quad = lane >> 4;

    const int r0 = tid >> 2;
    const int seg = ((tid & 3) ^ ((tid >> 3) & 3)) << 3;   // permuted k-chunk, elems
    const u16* Ag0 = A + (size_t)(row0 + r0) * K + seg;
    const u16* Ag1 = A + (size_t)(row0 + r0 + 64) * K + seg;
    const u16* Bg0 = Bt + (size_t)(col0 + r0) * K + seg;
    const u16* Bg1 = Bt + (size_t)(col0 + r0 + 64) * K + seg;

    const int pos = (quad ^ ((l16 >> 1) & 3)) << 3;        // frag read chunk, elems

    facc4 acc[4][4] = {};
    const int iters = K >> 5;          // >= 8 for all call sites

    u16* Ald = As + w * 512;
    u16* Bld = Bs + w * 512;
    #pragma unroll
    for (int pf = 0; pf < NBUF; ++pf) {
        const int ko = pf << 5;
        const int bo = pf << 12;
        gl_lds16(Ag0 + ko, Ald + bo);
        gl_lds16(Ag1 + ko, Ald + bo + 2048);
        gl_lds16(Bg0 + ko, Bld + bo);
        gl_lds16(Bg1 + ko, Bld + bo + 2048);
    }

    int b = 0;
    for (int it = 0; it < iters; ++it) {
        const int ahead = iters - 1 - it;
        if constexpr (NBUF == 3) {
            if (ahead >= 2)      asm volatile("s_waitcnt vmcnt(8)" ::: "memory");
            else if (ahead == 1) asm volatile("s_waitcnt vmcnt(4)" ::: "memory");
            else                 asm volatile("s_waitcnt vmcnt(0)" ::: "memory");
        } else {
            if (ahead >= 1)      asm volatile("s_waitcnt vmcnt(4)" ::: "memory");
            else                 asm volatile("s_waitcnt vmcnt(0)" ::: "memory");
        }
        __builtin_amdgcn_s_barrier();           // all waves' tile-it loads done
        asm volatile("" ::: "memory");          // pin ds_reads below barrier

        const u16* Ab = As + (b << 12);
        const u16* Bb = Bs + (b << 12);
        bfrag8 af[4], bf[4];
        #pragma unroll
        for (int i = 0; i < 4; ++i)
            af[i] = *(const bfrag8*)&Ab[(m_w + i * 16 + l16) * 32 + pos];
        #pragma unroll
        for (int j = 0; j < 4; ++j)
            bf[j] = *(const bfrag8*)&Bb[(n_w + j * 16 + l16) * 32 + pos];
        __builtin_amdgcn_s_setprio(1);
        #pragma unroll
        for (int i = 0; i < 4; ++i)
            #pragma unroll
            for (int j = 0; j < 4; ++j)
                acc[i][j] = __builtin_amdgcn_mfma_f32_16x16x32_bf16(
                    af[i], bf[j], acc[i][j], 0, 0, 0);
        __builtin_amdgcn_s_setprio(0);

        // fence: MFMAs (and thus their lgkm drains) complete before barrier,
        // so no wave can overwrite buf b while another still reads it (rule 18)
        __builtin_amdgcn_sched_barrier(0);
        asm volatile("" ::: "memory");
        __builtin_amdgcn_s_barrier();
        asm volatile("" ::: "memory");

        if (it + NBUF < iters) {                // refill just-consumed buffer
            const int ko = (it + NBUF) << 5;
            const int bo = b << 12;
            gl_lds16(Ag0 + ko, Ald + bo);
            gl_lds16(Ag1 + ko, Ald + bo + 2048);
            gl_lds16(Bg0 + ko, Bld + bo);
            gl_lds16(Bg1 + ko, Bld + bo + 2048);
        }
        b = (b == NBUF - 1) ? 0 : b + 1;
    }

    // hoisted per-thread column constants (4 distinct bias/pe values)
    float bv[4], pev[4];
    #pragma unroll
    for (int j = 0; j < 4; ++j) bv[j] = bias[col0 + n_w + j * 16 + l16];
    if (mode == MM_LAT) {
        #pragma unroll
        for (int j = 0; j < 4; ++j) pev[j] = pe[col0 + n_w + j * 16 + l16];
    }

    #pragma unroll
    for (int i = 0; i < 4; ++i) {
        #pragma unroll
        for (int r = 0; r < 4; ++r) {
            const int row = row0 + m_w + i * 16 + quad * 4 + r;
            const size_t base = (size_t)row * N + col0 + n_w + l16;
            float v[4];
            #pragma unroll
            for (int j = 0; j < 4; ++j) v[j] = acc[i][j][r] + bv[j];
            if (mode == MM_QKV) {
                const unsigned p01 = cvt_pk_bf16(v[0], v[1]);
                const unsigned p23 = cvt_pk_bf16(v[2], v[3]);
                Cb[base]      = (u16)p01; Cb[base + 16] = (u16)(p01 >> 16);
                Cb[base + 32] = (u16)p23; Cb[base + 48] = (u16)(p23 >> 16);
            } else if (mode == MM_RESID) {
                #pragma unroll
                for (int j = 0; j < 4; ++j) Cf[base + j * 16] += v[j];
            } else if (mode == MM_GELU_BF16) {
                #pragma unroll
                for (int j = 0; j < 4; ++j) v[j] = gelu_f(v[j]);
                const unsigned p01 = cvt_pk_bf16(v[0], v[1]);
                const unsigned p23 = cvt_pk_bf16(v[2], v[3]);
                Cb[base]      = (u16)p01; Cb[base + 16] = (u16)(p01 >> 16);
                Cb[base + 32] = (u16)p23; Cb[base + 48] = (u16)(p23 >> 16);
            } else if (mode == MM_GELU_F32) {
                #pragma unroll
                for (int j = 0; j < 4; ++j) Cf[base + j * 16] = gelu_f(v[j]);
            } else { // MM_LAT: gelu + PE, dual fp32/bf16 out
                #pragma unroll
                for (int j = 0; j < 4; ++j) {
                    v[j] = gelu_f(v[j]) + pev[j];
                    Cf[base + j * 16] = v[j];
                }
                const unsigned p01 = cvt_pk_bf16(v[0], v[1]);
                const unsigned p23 = cvt_pk_bf16(v[2], v[3]);
                Cb[base]      = (u16)p01; Cb[base + 16] = (u16)(p01 >> 16);
                Cb[base + 32] = (u16)p23; Cb[base + 48] = (u16)(p23 >> 16);
            }
        }
    }
}

// ---------------------------------------------------------------------------
// 256x128-tile variant, 8 waves (512 threads), wave grid 4Mx2N, same proven
// 64x64 wave subtile / chunk permutation / depth-3 counted-vmcnt pipeline.
// Serves all loop GEMMs (QKV, FF1, O-proj, FF2). 72KB LDS -> 2 blocks/CU.
// ---------------------------------------------------------------------------
__global__ __launch_bounds__(512) void mm256_kernel(
    const u16* __restrict__ A, const u16* __restrict__ Bt,
    const float* __restrict__ bias, float* __restrict__ Cf, u16* __restrict__ Cb,
    int N, int K, int mode, int gx)
{
    __shared__ __align__(16) u16 As[3 * 8192];   // 256 rows x 32 elems / buf
    __shared__ __align__(16) u16 Bs[3 * 4096];   // 128 rows x 32 elems / buf
    const int tid = threadIdx.x;

    const unsigned nwg = gridDim.x, cpx = nwg >> 3;
    const unsigned id = blockIdx.x;
    const unsigned swz = (id & 7u) * cpx + (id >> 3);
    const int bx = (int)(swz % (unsigned)gx);
    const int by = (int)(swz / (unsigned)gx);
    const int row0 = by * 256, col0 = bx * 128;

    const int lane = tid & 63, w = tid >> 6;
    const int m_w = (w & 3) << 6, n_w = (w >> 2) << 6;
    const int l16 = lane & 15, quad = lane >> 4;

    const int r0 = tid >> 2;                               // 0..127
    const int seg = ((tid & 3) ^ ((tid >> 3) & 3)) << 3;
    const u16* Ag0 = A + (size_t)(row0 + r0) * K + seg;
    const u16* Ag1 = A + (size_t)(row0 + r0 + 128) * K + seg;
    const u16* Bg0 = Bt + (size_t)(col0 + r0) * K + seg;

    const int pos = (quad ^ ((l16 >> 1) & 3)) << 3;

    facc4 acc[4][4] = {};
    const int iters = K >> 5;          // 16 (K=512) or 64 (K=2048)

    u16* Ald = As + w * 512;           // wave-slice DMA bases (64 chunks/wave)
    u16* Bld = Bs + w * 512;
    #pragma unroll
    for (int pf = 0; pf < 3; ++pf) {
        const int ko = pf << 5;
        gl_lds16(Ag0 + ko, Ald + pf * 8192);
        gl_lds16(Ag1 + ko, Ald + pf * 8192 + 4096);
        gl_lds16(Bg0 + ko, Bld + pf * 4096);
    }

    int b = 0;
    for (int it = 0; it < iters; ++it) {
        const int ahead = iters - 1 - it;   // 3 loads per tile per thread
        if (ahead >= 2)      asm volatile("s_waitcnt vmcnt(6)" ::: "memory");
        else if (ahead == 1) asm volatile("s_waitcnt vmcnt(3)" ::: "memory");
        else                 asm volatile("s_waitcnt vmcnt(0)" ::: "memory");
        __builtin_amdgcn_s_barrier();
        asm volatile("" ::: "memory");

        const u16* Ab = As + b * 8192;
        const u16* Bb = Bs + b * 4096;
        bfrag8 af[4], bf[4];
        #pragma unroll
        for (int i = 0; i < 4; ++i)
            af[i] = *(const bfrag8*)&Ab[(m_w + i * 16 + l16) * 32 + pos];
        #pragma unroll
        for (int j = 0; j < 4; ++j)
            bf[j] = *(const bfrag8*)&Bb[(n_w + j * 16 + l16) * 32 + pos];
        __builtin_amdgcn_s_setprio(1);
        #pragma unroll
        for (int i = 0; i < 4; ++i)
            #pragma unroll
            for (int j = 0; j < 4; ++j)
                acc[i][j] = __builtin_amdgcn_mfma_f32_16x16x32_bf16(
                    af[i], bf[j], acc[i][j], 0, 0, 0);
        __builtin_amdgcn_s_setprio(0);

        __builtin_amdgcn_sched_barrier(0);
        asm volatile("" ::: "memory");
        __builtin_amdgcn_s_barrier();
        asm volatile("" ::: "memory");

        if (it + 3 < iters) {
            const int ko = (it + 3) << 5;
            gl_lds16(Ag0 + ko, Ald + b * 8192);
            gl_lds16(Ag1 + ko, Ald + b * 8192 + 4096);
            gl_lds16(Bg0 + ko, Bld + b * 4096);
        }
        b = (b == 2) ? 0 : b + 1;
    }

    float bv[4];
    #pragma unroll
    for (int j = 0; j < 4; ++j) bv[j] = bias[col0 + n_w + j * 16 + l16];

    #pragma unroll
    for (int i = 0; i < 4; ++i) {
        #pragma unroll
        for (int r = 0; r < 4; ++r) {
            const int row = row0 + m_w + i * 16 + quad * 4 + r;
            const size_t base = (size_t)row * N + col0 + n_w + l16;
            float v[4];
            #pragma unroll
            for (int j = 0; j < 4; ++j) v[j] = acc[i][j][r] + bv[j];
            if (mode == MM_RESID) {
                #pragma unroll
                for (int j = 0; j < 4; ++j) Cf[base + j * 16] += v[j];
            } else {
                if (mode == MM_GELU_BF16) {
                    #pragma unroll
                    for (int j = 0; j < 4; ++j) v[j] = gelu_f(v[j]);
                }
                const unsigned p01 = cvt_pk_bf16(v[0], v[1]);
                const unsigned p23 = cvt_pk_bf16(v[2], v[3]);
                Cb[base]      = (u16)p01; Cb[base + 16] = (u16)(p01 >> 16);
                Cb[base + 32] = (u16)p23; Cb[base + 48] = (u16)(p23 >> 16);
            }
        }
    }
}

// positional encoding table pe[s*512+d], 102400 entries
__global__ __launch_bounds__(256) void pe_kernel(float* __restrict__ pe)
{
    const int idx = blockIdx.x * 256 + threadIdx.x;
    const int s = idx >> 9, d = idx & 511;
    const float ang = (float)s * expf((float)(d & ~1) * (-9.2103403719761836f / 512.0f));
    pe[idx] = (d & 1) ? cosf(ang) : sinf(ang);
}

// ---------------------------------------------------------------------------
// MFMA attention. Grid (qtile=4, h=8, b=128); 4 waves; wave = 16 queries.
// ---------------------------------------------------------------------------
__global__ __launch_bounds__(256) void attn_kernel(
    const u16* __restrict__ qkv, const float* __restrict__ tb,
    u16* __restrict__ ctxb)
{
    const int qt = blockIdx.x, h = blockIdx.y, b = blockIdx.z;
    const int tid = threadIdx.x;
    const int w = tid >> 6, lane = tid & 63;
    const int l16 = lane & 15, quad = lane >> 4;

    __shared__ __align__(16) u16 kv[16896];        // Ks[208][64] / Vt[64][264]
    __shared__ __align__(16) u16 Ps[4][16][232];   // softmaxed P per wave

    const size_t rowbase = (size_t)b * SEQ;
    const int q0w = qt * 64 + w * 16;

    for (int g = w; g < 26; g += 4) {
        const int c = g * 64 + lane;
        const int key = c >> 3, seg = c & 7;
        const int krow = key < 200 ? key : 199;
        gl_lds16(qkv + (rowbase + krow) * QKVS + 512 + h * 64 +
                 ((seg ^ (key & 7)) << 3),
                 kv + g * 512);
    }
    int qrow = (int)rowbase + q0w + l16;
    if (qrow > ROWS - 1) qrow = ROWS - 1;
    const u16* qp = qkv + (size_t)qrow * QKVS + h * 64 + quad * 8;
    bfrag8 aq0 = *(const bfrag8*)(qp);
    bfrag8 aq1 = *(const bfrag8*)(qp + 32);
    __syncthreads();

    facc4 sc[13];
    #pragma unroll
    for (int nt = 0; nt < 13; ++nt) {
        const int key = nt * 16 + l16, kk = key & 7;
        bfrag8 b0 = *(const bfrag8*)&kv[key * 64 + ((quad ^ kk) << 3)];
        bfrag8 b1 = *(const bfrag8*)&kv[key * 64 + (((4 + quad) ^ kk) << 3)];
        facc4 a = {};
        a = __builtin_amdgcn_mfma_f32_16x16x32_bf16(aq0, b0, a, 0, 0, 0);
        a = __builtin_amdgcn_mfma_f32_16x16x32_bf16(aq1, b1, a, 0, 0, 0);
        sc[nt] = a;
    }
    __syncthreads();

    for (int c = 0; c < 7; ++c) {
        const int key = c * 32 + (tid & 31);
        const int dkb = (tid >> 5) * 8;
        u16 vals[8];
        if (key < 200) {
            *(uint4*)vals = *(const uint4*)(qkv + (rowbase + key) * QKVS +
                                            1024 + h * 64 + dkb);
        } else {
            #pragma unroll
            for (int i = 0; i < 8; ++i) vals[i] = 0;
        }
        #pragma unroll
        for (int i = 0; i < 8; ++i)
            kv[(dkb + i) * VTS + key] = vals[i];
    }

    #pragma unroll
    for (int r = 0; r < 4; ++r) {
        const int i = q0w + quad * 4 + r;
        #pragma unroll
        for (int nt = 0; nt < 13; ++nt) {
            const int j = nt * 16 + l16;
            float s;
            if (j < 200) {
                const float tbv = (i < 200) ? tb[(h * 200 + i) * 200 + j] : 0.f;
                s = sc[nt][r] * 0.125f + tbv;
            } else s = -INFINITY;
            sc[nt][r] = s;
        }
        float m = sc[0][r];
        #pragma unroll
        for (int nt = 1; nt < 13; ++nt) m = fmaxf(m, sc[nt][r]);
        #pragma unroll
        for (int off = 8; off > 0; off >>= 1) m = fmaxf(m, __shfl_xor(m, off, 64));
        float ssum = 0.f;
        #pragma unroll
        for (int nt = 0; nt < 13; ++nt) {
            const float e = __expf(sc[nt][r] - m);
            sc[nt][r] = e; ssum += e;
        }
        #pragma unroll
        for (int off = 8; off > 0; off >>= 1) ssum += __shfl_xor(ssum, off, 64);
        const float inv = 1.0f / ssum;
        u16* psr = &Ps[w][quad * 4 + r][0];
        #pragma unroll
        for (int nt = 0; nt < 12; nt += 2) {
            const unsigned pq = cvt_pk_bf16(sc[nt][r] * inv, sc[nt + 1][r] * inv);
            psr[nt * 16 + l16]       = (u16)pq;
            psr[(nt + 1) * 16 + l16] = (u16)(pq >> 16);
        }
        psr[192 + l16] = f2bf(sc[12][r] * inv);
        psr[208 + l16] = 0;
    }
    __syncthreads();

    facc4 pacc[4] = {};
    for (int ks = 0; ks < 7; ++ks) {
        bfrag8 ap = *(const bfrag8*)&Ps[w][l16][ks * 32 + quad * 8];
        #pragma unroll
        for (int nt = 0; nt < 4; ++nt) {
            const int dkrow = nt * 16 + l16;
            bfrag8 bv = *(const bfrag8*)&kv[dkrow * VTS + ks * 32 + quad * 8];
            pacc[nt] = __builtin_amdgcn_mfma_f32_16x16x32_bf16(ap, bv, pacc[nt], 0, 0, 0);
        }
    }

    #pragma unroll
    for (int r = 0; r < 4; ++r) {
        const int i = q0w + quad * 4 + r;
        if (i < 200) {
            const unsigned p01 = cvt_pk_bf16(pacc[0][r], pacc[1][r]);
            const unsigned p23 = cvt_pk_bf16(pacc[2][r], pacc[3][r]);
            u16* cp = ctxb + (rowbase + i) * 512 + h * 64 + l16;
            cp[0]  = (u16)p01; cp[16] = (u16)(p01 >> 16);
            cp[32] = (u16)p23; cp[48] = (u16)(p23 >> 16);
        }
    }
}

// ---------------------------------------------------------------------------
// Transpose-convert W [K,N] fp32 -> Wt [N,K] bf16, batched over blockIdx.z
// ---------------------------------------------------------------------------
__global__ __launch_bounds__(256) void tconv_kernel(
    const float* __restrict__ W, u16* __restrict__ O, int K, int N,
    size_t wStride, size_t oStride)
{
    __shared__ u16 T[64][80];
    const float* Wz = W + wStride * blockIdx.z;
    u16* Oz = O + oStride * blockIdx.z;
    const int n0 = blockIdx.x * 64, k0 = blockIdx.y * 64, t = threadIdx.x;
    {
        const int kr = t >> 2, seg = t & 3;
        const float* wp = Wz + (size_t)(k0 + kr) * N + n0 + seg * 16;
        alignas(16) unsigned tmp[8];
        #pragma unroll
        for (int q = 0; q < 4; ++q) {
            float4 f = ((const float4*)wp)[q];
            tmp[q * 2]     = cvt_pk_bf16(f.x, f.y);
            tmp[q * 2 + 1] = cvt_pk_bf16(f.z, f.w);
        }
        *(uint4*)&T[kr][seg * 16]     = *(uint4*)&tmp[0];
        *(uint4*)&T[kr][seg * 16 + 8] = *(uint4*)&tmp[4];
    }
    __syncthreads();
    {
        const int n = t >> 2, kseg = t & 3;
        alignas(16) u16 o[16];
        #pragma unroll
        for (int i = 0; i < 16; ++i) o[i] = T[kseg * 16 + i][n];
        uint4* op = (uint4*)(Oz + (size_t)(n0 + n) * K + k0 + kseg * 16);
        op[0] = *(uint4*)&o[0];
        op[1] = *(uint4*)&o[8];
    }
}

// qkvo batch: z = layer*4 + {q,k,v,o}, all 512x512
__global__ __launch_bounds__(256) void tconv4_kernel(
    const float* __restrict__ Wq, const float* __restrict__ Wk,
    const float* __restrict__ Wv, const float* __restrict__ Wo,
    u16* __restrict__ Out)
{
    __shared__ u16 T[64][80];
    const int z = blockIdx.z, layer = z >> 2, m = z & 3;
    const float* W = (m == 0 ? Wq : m == 1 ? Wk : m == 2 ? Wv : Wo)
                     + (size_t)layer * 262144;
    u16* O = Out + (size_t)z * 262144;
    const int n0 = blockIdx.x * 64, k0 = blockIdx.y * 64, t = threadIdx.x;
    {
        const int kr = t >> 2, seg = t & 3;
        const float* wp = W + (size_t)(k0 + kr) * 512 + n0 + seg * 16;
        alignas(16) unsigned tmp[8];
        #pragma unroll
        for (int q = 0; q < 4; ++q) {
            float4 f = ((const float4*)wp)[q];
            tmp[q * 2]     = cvt_pk_bf16(f.x, f.y);
            tmp[q * 2 + 1] = cvt_pk_bf16(f.z, f.w);
        }
        *(uint4*)&T[kr][seg * 16]     = *(uint4*)&tmp[0];
        *(uint4*)&T[kr][seg * 16 + 8] = *(uint4*)&tmp[4];
    }
    __syncthreads();
    {
        const int n = t >> 2, kseg = t & 3;
        alignas(16) u16 o[16];
        #pragma unroll
        for (int i = 0; i < 16; ++i) o[i] = T[kseg * 16 + i][n];
        uint4* op = (uint4*)(O + (size_t)(n0 + n) * 512 + k0 + kseg * 16);
        op[0] = *(uint4*)&o[0];
        op[1] = *(uint4*)&o[8];
    }
}

// concat biases: bqkv[l][1536] = [bq[l] | bk[l] | bv[l]]
__global__ __launch_bounds__(256) void bqkv_kernel(
    const float* __restrict__ bq, const float* __restrict__ bk,
    const float* __restrict__ bv, float* __restrict__ o)
{
    const int l = blockIdx.x, t = threadIdx.x;
    for (int c = t; c < 1536; c += 256) {
        float v = (c < 512) ? bq[l * 512 + c]
                : (c < 1024) ? bk[l * 512 + c - 512]
                             : bv[l * 512 + c - 1024];
        o[l * 1536 + c] = v;
    }
}

// LayerNorm: 1 wave per row, 4 rows/block, vectorized, shuffle-only reduce
__global__ __launch_bounds__(256) void ln_kernel(
    float* __restrict__ x, const float* __restrict__ g,
    const float* __restrict__ bb, u16* __restrict__ xb)
{
    const int w = threadIdx.x >> 6, lane = threadIdx.x & 63;
    const size_t row = (size_t)blockIdx.x * 4 + w;
    float* xr = x + row * DMODEL;
    u16* xbr = xb + row * DMODEL;
    const int c = lane * 8;
    float4 a = *(const float4*)(xr + c);
    float4 b = *(const float4*)(xr + c + 4);
    float s = a.x + a.y + a.z + a.w + b.x + b.y + b.z + b.w;
    #pragma unroll
    for (int off = 32; off > 0; off >>= 1) s += __shfl_xor(s, off, 64);
    const float mu = s * (1.0f / 512.0f);
    a.x -= mu; a.y -= mu; a.z -= mu; a.w -= mu;
    b.x -= mu; b.y -= mu; b.z -= mu; b.w -= mu;
    float v = a.x * a.x + a.y * a.y + a.z * a.z + a.w * a.w
            + b.x * b.x + b.y * b.y + b.z * b.z + b.w * b.w;
    #pragma unroll
    for (int off = 32; off > 0; off >>= 1) v += __shfl_xor(v, off, 64);
    const float rstd = rsqrtf(v * (1.0f / 512.0f) + 1e-5f);
    float4 g0 = *(const float4*)(g + c), g1 = *(const float4*)(g + c + 4);
    float4 b0 = *(const float4*)(bb + c), b1 = *(const float4*)(bb + c + 4);
    float4 o0, o1;
    o0.x = a.x * rstd * g0.x + b0.x; o0.y = a.y * rstd * g0.y + b0.y;
    o0.z = a.z * rstd * g0.z + b0.z; o0.w = a.w * rstd * g0.w + b0.w;
    o1.x = b.x * rstd * g1.x + b1.x; o1.y = b.y * rstd * g1.y + b1.y;
    o1.z = b.z * rstd * g1.z + b1.z; o1.w = b.w * rstd * g1.w + b1.w;
    *(float4*)(xr + c) = o0;
    *(float4*)(xr + c + 4) = o1;
    uint4 ob;
    ob.x = cvt_pk_bf16(o0.x, o0.y);
    ob.y = cvt_pk_bf16(o0.z, o0.w);
    ob.z = cvt_pk_bf16(o1.x, o1.y);
    ob.w = cvt_pk_bf16(o1.z, o1.w);
    *(uint4*)(xbr + c) = ob;
}

__global__ __launch_bounds__(256) void concat_z_kernel(
    const float* __restrict__ zs, const float* __restrict__ zk, u16* __restrict__ z)
{
    const int b = blockIdx.x, t = threadIdx.x;
    z[b * 256 + t] = f2bf((t < 128) ? zs[b * 128 + t] : zk[b * 128 + t - 128]);
}

__global__ __launch_bounds__(64) void traj_head_kernel(
    const float* __restrict__ t1, const float* __restrict__ Wp2,
    const float* __restrict__ bp2, float* __restrict__ out)
{
    const int r = blockIdx.x, t = threadIdx.x;
    __shared__ float red[6][64];
    float p[6] = {};
    const float* tr = t1 + (size_t)r * 256;
    for (int kk = t; kk < 256; kk += 64) {
        float tv = tr[kk];
        #pragma unroll
        for (int c = 0; c < 6; ++c) p[c] = fmaf(tv, Wp2[kk * 6 + c], p[c]);
    }
    #pragma unroll
    for (int c = 0; c < 6; ++c) red[c][t] = p[c];
    __syncthreads();
    if (t < 6) {
        float a = 0.f;
        for (int j = 0; j < 64; ++j) a += red[t][j];
        out[(size_t)r * 6 + t] = a + bp2[t];
    }
}

__global__ __launch_bounds__(256) void sig_head_kernel(
    const float* __restrict__ zs, const float* __restrict__ zk,
    const float* __restrict__ Ws1, const float* __restrict__ bs1,
    const float* __restrict__ Ws2, const float* __restrict__ bs2,
    float* __restrict__ out)
{
    const int b = blockIdx.x, t = threadIdx.x;
    __shared__ float zrow[256];
    __shared__ float h1[256];
    zrow[t] = (t < 128) ? zs[b * 128 + t] : zk[b * 128 + t - 128];
    __syncthreads();
    float acc = bs1[t];
    for (int kk = 0; kk < 256; ++kk) acc = fmaf(zrow[kk], Ws1[kk * 256 + t], acc);
    h1[t] = gelu_f(acc);
    __syncthreads();
    if (t < 5) {
        float a = bs2[t];
        for (int kk = 0; kk < 256; ++kk) a = fmaf(h1[kk], Ws2[kk * 5 + t], a);
        out[b * 5 + t] = a;
    }
}

extern "C" void kernel_launch(void* const* d_in, const int* in_sizes, int n_in,
                              void* d_out, int out_size, void* d_ws, size_t ws_size,
                              hipStream_t stream) {
    const float* z_style   = (const float*)d_in[0];
    const float* z_skill   = (const float*)d_in[1];
    const float* W_lat     = (const float*)d_in[2];
    const float* b_lat     = (const float*)d_in[3];
    const float* temp_bias = (const float*)d_in[4];
    const float* Wq  = (const float*)d_in[5];
    const float* bq  = (const float*)d_in[6];
    const float* Wk  = (const float*)d_in[7];
    const float* bk  = (const float*)d_in[8];
    const float* Wv  = (const float*)d_in[9];
    const float* bv  = (const float*)d_in[10];
    const float* Wo  = (const float*)d_in[11];
    const float* bo  = (const float*)d_in[12];
    const float* g1  = (const float*)d_in[13];
    const float* be1 = (const float*)d_in[14];
    const float* g2  = (const float*)d_in[15];
    const float* be2 = (const float*)d_in[16];
    const float* W1  = (const float*)d_in[17];
    const float* bf1 = (const float*)d_in[18];
    const float* W2  = (const float*)d_in[19];
    const float* bf2 = (const float*)d_in[20];
    const float* Wp1 = (const float*)d_in[21];
    const float* bp1 = (const float*)d_in[22];
    const float* Wp2 = (const float*)d_in[23];
    const float* bp2 = (const float*)d_in[24];
    const float* Ws1 = (const float*)d_in[25];
    const float* bs1 = (const float*)d_in[26];
    const float* Ws2 = (const float*)d_in[27];
    const float* bs2 = (const float*)d_in[28];
    float* out = (float*)d_out;

    // ---- workspace layout (bytes), total ~222.1 MB ----
    char* Wb = (char*)d_ws;
    float* x     = (float*)(Wb + 0);             // [25600,512] fp32 residual
    u16*  xb     = (u16*)(Wb + 52428800);        // [25600,512] bf16 (LN out)
    u16*  qkv    = (u16*)(Wb + 78643200);        // [25600,1536] bf16
    u16*  cx     = (u16*)(Wb + 157286400);       // ctx bf16 [25600,512]
    u16*  ff1b   = (u16*)(Wb + 78643200);        // [25600,2048] overlays qkv+cx
    u16*  wlatT  = (u16*)(Wb + 78643200);        // [102400,256] pre-loop only
    float* t1    = (float*)(Wb + 157286400);     // head scratch (cx dead)
    u16*  qkvoT  = (u16*)(Wb + 183500800);       // 24 x [512,512]
    u16*  w1T    = (u16*)(Wb + 196083712);       // 6 x [2048,512]
    u16*  w2T    = (u16*)(Wb + 208666624);       // 6 x [512,2048]
    u16*  wp1T   = (u16*)(Wb + 221249536);       // [256,512]
    float* bqkv  = (float*)(Wb + 221511680);     // [6,1536]
    u16*  zbb    = (u16*)(Wb + 221548544);       // [128,256]
    float* pe    = (float*)(Wb + 221614080);     // [102400] fp32 PE table

    // ---- weight conversion (every launch; inputs restored each call) ----
    tconv4_kernel<<<dim3(8, 8, 24), 256, 0, stream>>>(Wq, Wk, Wv, Wo, qkvoT);
    tconv_kernel<<<dim3(32, 8, 6), 256, 0, stream>>>(W1, w1T, DMODEL, DFF,
                                                     (size_t)DMODEL * DFF, (size_t)DMODEL * DFF);
    tconv_kernel<<<dim3(8, 32, 6), 256, 0, stream>>>(W2, w2T, DFF, DMODEL,
                                                     (size_t)DMODEL * DFF, (size_t)DMODEL * DFF);
    tconv_kernel<<<dim3(1600, 4, 1), 256, 0, stream>>>(W_lat, wlatT, LATDIM, DMODEL * SEQ, 0, 0);
    tconv_kernel<<<dim3(4, 8, 1), 256, 0, stream>>>(Wp1, wp1T, DMODEL, 256, 0, 0);
    bqkv_kernel<<<NLAYER, 256, 0, stream>>>(bq, bk, bv, bqkv);
    concat_z_kernel<<<BATCH, 256, 0, stream>>>(z_style, z_skill, zbb);
    pe_kernel<<<400, 256, 0, stream>>>(pe);

    // x = gelu(z @ W_lat + b_lat) + pe  (dual fp32/bf16); NBUF=2 -> 5 blk/CU
    // -> 160 slots/XCD vs 100 blocks/XCD: single generation, no tail
    mm_kernel<2><<<dim3(800), 256, 0, stream>>>(
        zbb, wlatT, b_lat, x, xb, pe, BATCH, DMODEL * SEQ, LATDIM, MM_LAT, 800);

    for (int l = 0; l < NLAYER; ++l) {
        mm256_kernel<<<dim3(12 * 100), 512, 0, stream>>>(
            xb, qkvoT + (size_t)l * 4 * 262144, bqkv + l * 1536, nullptr, qkv,
            QKVS, DMODEL, MM_QKV, 12);
        attn_kernel<<<dim3(4, NHEAD, BATCH), 256, 0, stream>>>(qkv, temp_bias, cx);
        mm256_kernel<<<dim3(4 * 100), 512, 0, stream>>>(
            cx, qkvoT + (size_t)(l * 4 + 3) * 262144, bo + l * DMODEL, x, nullptr,
            DMODEL, DMODEL, MM_RESID, 4);
        ln_kernel<<<ROWS / 4, 256, 0, stream>>>(x, g1 + l * DMODEL, be1 + l * DMODEL, xb);
        mm256_kernel<<<dim3(16 * 100), 512, 0, stream>>>(
            xb, w1T + (size_t)l * DMODEL * DFF, bf1 + l * DFF, nullptr, ff1b,
            DFF, DMODEL, MM_GELU_BF16, 16);
        mm256_kernel<<<dim3(4 * 100), 512, 0, stream>>>(
            ff1b, w2T + (size_t)l * DMODEL * DFF, bf2 + l * DMODEL, x, nullptr,
            DMODEL, DFF, MM_RESID, 4);
        ln_kernel<<<ROWS / 4, 256, 0, stream>>>(x, g2 + l * DMODEL, be2 + l * DMODEL, xb);
    }

    // heads
    mm_kernel<3><<<dim3(2 * 200), 256, 0, stream>>>(
        xb, wp1T, bp1, t1, nullptr, pe, ROWS, 256, DMODEL, MM_GELU_F32, 2);
    traj_head_kernel<<<ROWS, 64, 0, stream>>>(t1, Wp2, bp2, out);
    sig_head_kernel<<<BATCH, 256, 0, stream>>>(z_style, z_skill, Ws1, bs1, Ws2, bs2,
                                               out + (size_t)ROWS * OUTDIM);
}